// Round 9
// baseline (947.347 us; speedup 1.0000x reference)
//
#include <hip/hip_runtime.h>

typedef unsigned short ushort8 __attribute__((ext_vector_type(8)));
typedef short s16x8 __attribute__((ext_vector_type(8)));
typedef float f32x4 __attribute__((ext_vector_type(4)));

#define AS1 __attribute__((address_space(1)))
#define AS3 __attribute__((address_space(3)))

#define B_    4
#define S_    2048
#define HID_  2048
#define NH_   16
#define NKV_  8
#define D_    128
#define RK_   16
#define SCALING_ 0.08838834764831845f   // 128^-0.5
#define LOG2E_   1.4426950408889634f
#define NEGBIG   -1.0e30f

__device__ __forceinline__ float bf2f(unsigned short u) {
  union { unsigned int i; float f; } x; x.i = ((unsigned int)u) << 16; return x.f;
}
__device__ __forceinline__ unsigned short f2bf(float f) {
  union { float f; unsigned int i; } x; x.f = f;
  unsigned int r = x.i + 0x7fffu + ((x.i >> 16) & 1u);
  return (unsigned short)(r >> 16);
}

// ---------------------------------------------------------------------------
// f32 -> bf16 conversion, 8 elems/thread, grid-stride.
// ---------------------------------------------------------------------------
__global__ __launch_bounds__(256) void cvt_bf16(const float* __restrict__ in,
                                                unsigned short* __restrict__ out,
                                                int n8) {
  int i = blockIdx.x * 256 + threadIdx.x;
  const int stride = gridDim.x * 256;
  for (; i < n8; i += stride) {
    const float4 a = ((const float4*)in)[i * 2];
    const float4 b = ((const float4*)in)[i * 2 + 1];
    ushort8 u;
    u[0] = f2bf(a.x); u[1] = f2bf(a.y); u[2] = f2bf(a.z); u[3] = f2bf(a.w);
    u[4] = f2bf(b.x); u[5] = f2bf(b.y); u[6] = f2bf(b.z); u[7] = f2bf(b.w);
    *(ushort8*)&out[i * 8] = u;
  }
}

// ---------------------------------------------------------------------------
// Fused low-rank weights, bf16 out [384][2048]:
//   rows h*16+r       (h<16): Wkr = sum_d W_k[(h>>1)*128+d][c] * Vr[h][d][r]
//   rows 256+g*16+r   (g<8) : Wvz = sum_d W_v[g*128+d][c]      * Zv[g][d][r]
// ---------------------------------------------------------------------------
__global__ __launch_bounds__(256) void wfuse(const float* __restrict__ W_k,
                                             const float* __restrict__ W_v,
                                             const float* __restrict__ Vr,
                                             const float* __restrict__ Zv,
                                             unsigned short* __restrict__ Wf) {
  const int idx = blockIdx.x;
  const int cc = blockIdx.y * 256;
  const int tid = threadIdx.x;
  const bool isK = idx < 16;
  const int hg = isK ? idx : (idx - 16);
  const int wrow0 = isK ? (idx * 16) : (256 + (idx - 16) * 16);
  const float* W = isK ? &W_k[(size_t)((hg >> 1) * 128) * HID_]
                       : &W_v[(size_t)(hg * 128) * HID_];
  const float* P = isK ? &Vr[(size_t)hg * 128 * 16] : &Zv[(size_t)hg * 128 * 16];
  __shared__ float Wl[32][257];
  float acc[16] = {};
  for (int d0 = 0; d0 < 128; d0 += 32) {
    __syncthreads();
#pragma unroll 8
    for (int dd = 0; dd < 32; ++dd)
      Wl[dd][tid] = W[(size_t)(d0 + dd) * HID_ + cc + tid];
    __syncthreads();
#pragma unroll 8
    for (int dd = 0; dd < 32; ++dd) {
      const float w = Wl[dd][tid];
#pragma unroll
      for (int r = 0; r < 16; ++r) acc[r] += w * P[(d0 + dd) * 16 + r];
    }
  }
#pragma unroll
  for (int r = 0; r < 16; ++r)
    Wf[(size_t)(wrow0 + r) * HID_ + cc + tid] = f2bf(acc[r]);
}

// ---------------------------------------------------------------------------
// MFMA GEMM: C[M,N] = A[M,K] @ B[N,K]^T, A,B bf16, C f32 or bf16.
// 128x128 tile, BK=64, 4 waves, XCD chunk swizzle (grid blocks % 8 == 0).
// ---------------------------------------------------------------------------
template<bool CBF>
__global__ __launch_bounds__(256) void gemm_mfma(const unsigned short* __restrict__ A,
                                                 const unsigned short* __restrict__ Bb,
                                                 void* __restrict__ C_,
                                                 int M, int N, int K) {
  __shared__ unsigned short Ash[128 * 64];
  __shared__ unsigned short Bsh[128 * 64];
  const int tid = threadIdx.x;
  const int w = tid >> 6, l = tid & 63, lg = l >> 4, ll = l & 15;
  const int wr = w >> 1, wc = w & 1;
  const int flat = blockIdx.y * gridDim.x + blockIdx.x;
  const int cpx = (gridDim.x * gridDim.y) >> 3;
  const int swz = (flat & 7) * cpx + (flat >> 3);
  const int bm = (swz / gridDim.x) * 128, bn = (swz % gridDim.x) * 128;

  f32x4 acc[4][4];
#pragma unroll
  for (int i = 0; i < 4; i++)
#pragma unroll
    for (int j = 0; j < 4; j++) acc[i][j] = (f32x4){0.f, 0.f, 0.f, 0.f};

  const int srow = tid >> 3;
  const int sslot = tid & 7;

  for (int k0 = 0; k0 < K; k0 += 64) {
    __syncthreads();
#pragma unroll
    for (int c = 0; c < 4; ++c) {
      const int row = c * 32 + srow;
      const int ss = sslot ^ (row & 7);
      const unsigned short* srcA = &A[(size_t)(bm + row) * K + k0 + ss * 8];
      const unsigned short* srcB = &Bb[(size_t)(bn + row) * K + k0 + ss * 8];
      char* dstA = ((char*)Ash) + c * 4096 + w * 1024;
      char* dstB = ((char*)Bsh) + c * 4096 + w * 1024;
      __builtin_amdgcn_global_load_lds((const AS1 void*)srcA, (AS3 void*)dstA, 16, 0, 0);
      __builtin_amdgcn_global_load_lds((const AS1 void*)srcB, (AS3 void*)dstB, 16, 0, 0);
    }
    __syncthreads();

#pragma unroll
    for (int ks = 0; ks < 2; ++ks) {
      s16x8 af[4], bf_[4];
#pragma unroll
      for (int mi = 0; mi < 4; ++mi) {
        const int row = wr * 64 + mi * 16 + ll;
        af[mi] = *(const s16x8*)&Ash[row * 64 + (((ks * 4 + lg) ^ (row & 7)) * 8)];
      }
#pragma unroll
      for (int ni = 0; ni < 4; ++ni) {
        const int row = wc * 64 + ni * 16 + ll;
        bf_[ni] = *(const s16x8*)&Bsh[row * 64 + (((ks * 4 + lg) ^ (row & 7)) * 8)];
      }
#pragma unroll
      for (int mi = 0; mi < 4; ++mi)
#pragma unroll
        for (int ni = 0; ni < 4; ++ni)
          acc[mi][ni] = __builtin_amdgcn_mfma_f32_16x16x32_bf16(af[mi], bf_[ni], acc[mi][ni], 0, 0, 0);
    }
  }

#pragma unroll
  for (int mi = 0; mi < 4; ++mi)
#pragma unroll
    for (int ni = 0; ni < 4; ++ni)
#pragma unroll
      for (int j = 0; j < 4; ++j) {
        const int row = bm + wr * 64 + mi * 16 + lg * 4 + j;
        const int col = bn + wc * 64 + ni * 16 + ll;
        if (CBF) ((unsigned short*)C_)[(size_t)row * N + col] = f2bf(acc[mi][ni][j]);
        else     ((float*)C_)[(size_t)row * N + col] = acc[mi][ni][j];
      }
}

// ---------------------------------------------------------------------------
// In-place RoPE on bf16 q, folding SCALING*log2(e).
// ---------------------------------------------------------------------------
__global__ __launch_bounds__(256) void rope_q(unsigned short* __restrict__ q,
                                              const float* __restrict__ cosT,
                                              const float* __restrict__ sinT) {
  const int p = blockIdx.x * 256 + threadIdx.x;
  const int d = p & 63;
  const int h = (p >> 6) & 15;
  const int s = (p >> 10) & 2047;
  const int b = p >> 21;
  const size_t base = (((size_t)b * S_ + s) * NH_ + h) * D_ + d;
  const float x1 = bf2f(q[base]), x2 = bf2f(q[base + 64]);
  const float c = cosT[s * 64 + d], sn = sinT[s * 64 + d];
  const float sc = SCALING_ * LOG2E_;
  q[base]      = f2bf((x1 * c - x2 * sn) * sc);
  q[base + 64] = f2bf((x1 * sn + x2 * c) * sc);
}

// ---------------------------------------------------------------------------
// Expand pk (fused [M][384] f32, cols h*16+r) -> k_rot bf16 (B,NH,S,D) +RoPE.
// ---------------------------------------------------------------------------
__global__ __launch_bounds__(256) void expand_k(const float* __restrict__ pkpv,
                                                const float* __restrict__ Vr,
                                                const float* __restrict__ cosT,
                                                const float* __restrict__ sinT,
                                                unsigned short* __restrict__ kr) {
  const int s0 = blockIdx.x * 32, h = blockIdx.y, b = blockIdx.z;
  const int tid = threadIdx.x;
  __shared__ float pkS[32][17];
  if (tid < 128) {
    const int r_ = tid >> 2, c4 = (tid & 3) * 4;
    float4 v = *(const float4*)&pkpv[(size_t)(b * S_ + s0 + r_) * 384 + h * 16 + c4];
    pkS[r_][c4 + 0] = v.x; pkS[r_][c4 + 1] = v.y;
    pkS[r_][c4 + 2] = v.z; pkS[r_][c4 + 3] = v.w;
  }
  __syncthreads();
  const int row = tid >> 3, dl = tid & 7;
  float kh[16];
#pragma unroll
  for (int j = 0; j < 16; j++) {
    const int d = dl + 8 * j;
    const float4* w = (const float4*)&Vr[((size_t)h * D_ + d) * RK_];
    float a = 0.f;
#pragma unroll
    for (int q4 = 0; q4 < 4; q4++) {
      float4 wv = w[q4];
      a += pkS[row][q4 * 4 + 0] * wv.x + pkS[row][q4 * 4 + 1] * wv.y
         + pkS[row][q4 * 4 + 2] * wv.z + pkS[row][q4 * 4 + 3] * wv.w;
    }
    kh[j] = a;
  }
  const int pos = s0 + row;
  const size_t o = (((size_t)b * NH_ + h) * S_ + pos) * D_;
#pragma unroll
  for (int j = 0; j < 8; j++) {
    const int d = dl + 8 * j;
    const float c = cosT[pos * 64 + d], sn = sinT[pos * 64 + d];
    kr[o + d]      = f2bf(kh[j] * c - kh[j + 8] * sn);
    kr[o + d + 64] = f2bf(kh[j] * sn + kh[j + 8] * c);
  }
}

// ---------------------------------------------------------------------------
// Expand pv (cols 256+g*16+r) -> v_hat bf16 (B,NKV,S,D).
// ---------------------------------------------------------------------------
__global__ __launch_bounds__(256) void expand_v(const float* __restrict__ pkpv,
                                                const float* __restrict__ Zv,
                                                unsigned short* __restrict__ vh) {
  const int s0 = blockIdx.x * 32, g = blockIdx.y, b = blockIdx.z;
  const int tid = threadIdx.x;
  __shared__ float pvS[32][17];
  if (tid < 128) {
    const int r_ = tid >> 2, c4 = (tid & 3) * 4;
    float4 v = *(const float4*)&pkpv[(size_t)(b * S_ + s0 + r_) * 384 + 256 + g * 16 + c4];
    pvS[r_][c4 + 0] = v.x; pvS[r_][c4 + 1] = v.y;
    pvS[r_][c4 + 2] = v.z; pvS[r_][c4 + 3] = v.w;
  }
  __syncthreads();
  const int row = tid >> 3, dl = tid & 7;
  const size_t o = (((size_t)b * NKV_ + g) * S_ + s0 + row) * D_;
#pragma unroll
  for (int j = 0; j < 16; j++) {
    const int d = dl + 8 * j;
    const float4* w = (const float4*)&Zv[((size_t)g * D_ + d) * RK_];
    float a = 0.f;
#pragma unroll
    for (int q4 = 0; q4 < 4; q4++) {
      float4 wv = w[q4];
      a += pvS[row][q4 * 4 + 0] * wv.x + pvS[row][q4 * 4 + 1] * wv.y
         + pvS[row][q4 * 4 + 2] * wv.z + pvS[row][q4 * 4 + 3] * wv.w;
    }
    vh[o + d] = f2bf(a);
  }
}

// ---------------------------------------------------------------------------
// MFMA flash attention v4: small-footprint geometry for residency.
// 256 thr = 4 waves x 16 q-rows (QBLK 64), KVBLK 32, full double-buffering.
// LDS 36KB (K 2x8 + Vt 2x8 + Ps 4) -> multiple blocks/CU (round-8's 80KB was
// an exact-160KB fit -> ~1 block/CU, 8.6% occupancy). Natural VGPR (~150-190,
// no launch-bounds min). Same schedule: issue K(gload_lds)+V(regs) for t+1,
// compute t, write V late, ONE barrier. Defer-max log2 softmax, cvt_pk pack.
// ---------------------------------------------------------------------------
__global__ __launch_bounds__(256) void attn_mfma(const unsigned short* __restrict__ q,
                                                 const unsigned short* __restrict__ kr,
                                                 const unsigned short* __restrict__ vh,
                                                 unsigned short* __restrict__ out) {
  const int flat = ((int)blockIdx.z * 16 + (int)blockIdx.y) * 32 + (int)blockIdx.x;
  const int swz = (flat & 7) * 256 + (flat >> 3);   // XCD chunking over 2048 blocks
  const int qt = 31 - (swz & 31);                   // big q-tiles first
  const int h = (swz >> 5) & 15;
  const int b = swz >> 9;
  const int g = h >> 1;
  const int tid = threadIdx.x;
  const int w = tid >> 6, l = tid & 63, lg = l >> 4, ll = l & 15;

  __shared__ unsigned short Klds[2][32 * 128];  // [key][d], slot^(row&7) of 16
  __shared__ unsigned short Vt[2][128 * 32];    // [d][key], slot^((d>>2)&3) of 4
  __shared__ unsigned short Ps[4][16 * 32];     // per-wave P, slot^((row>>2)&3)

  const int qr0 = qt * 64 + w * 16;
  const int ktmax = 2 * qt + 1;
  const int kmy = 2 * qt + (w >> 1);

  // Q fragments (pre-scaled with SCALING*log2e by rope_q): row ll, k-chunk lg
  s16x8 qf[4];
#pragma unroll
  for (int ks = 0; ks < 4; ++ks)
    qf[ks] = *(const s16x8*)&q[(((size_t)b * S_ + qr0 + ll) * NH_ + h) * D_ + ks * 32 + lg * 8];

  f32x4 o[8];
#pragma unroll
  for (int nd = 0; nd < 8; ++nd) o[nd] = (f32x4){0.f, 0.f, 0.f, 0.f};
  float m_[4], l_[4];
#pragma unroll
  for (int j = 0; j < 4; ++j) { m_[j] = NEGBIG; l_[j] = 0.f; }

  const unsigned short* kbase = &kr[(((size_t)b * NH_ + h) * S_) * D_];
  const unsigned short* vbase = &vh[(((size_t)b * NKV_ + g) * S_) * D_];
  const int vk = (tid & 15) * 2;        // key pair
  const int d0v = (tid >> 4) * 8;       // 8-wide d block

  // ---- prologue: stage tile 0
  ushort8 va, vb2;
  {
#pragma unroll
    for (int c = 0; c < 2; ++c) {
      const int ro = c * 16 + w * 4 + lg;
      const int ss = ll ^ (ro & 7);
      const unsigned short* src = kbase + ro * D_ + ss * 8;
      char* dst = ((char*)&Klds[0][0]) + c * 4096 + w * 1024;
      __builtin_amdgcn_global_load_lds((const AS1 void*)src, (AS3 void*)dst, 16, 0, 0);
    }
    const unsigned short* v0 = vbase + (size_t)vk * D_ + d0v;
    va = *(const ushort8*)v0; vb2 = *(const ushort8*)(v0 + D_);
#pragma unroll
    for (int j = 0; j < 8; ++j) {
      const int d = d0v + j;
      *(unsigned int*)&Vt[0][d * 32 + (((vk >> 3) ^ ((d >> 2) & 3)) * 8) + (vk & 7)] =
          (unsigned int)va[j] | ((unsigned int)vb2[j] << 16);
    }
  }
  __syncthreads();

  for (int kt = 0; kt <= ktmax; ++kt) {
    const int p = kt & 1;
    // ---- issue next-tile staging (K direct to LDS, V to regs)
    if (kt < ktmax) {
      const unsigned short* kb2 = kbase + (size_t)(kt + 1) * 32 * D_;
#pragma unroll
      for (int c = 0; c < 2; ++c) {
        const int ro = c * 16 + w * 4 + lg;
        const int ss = ll ^ (ro & 7);
        const unsigned short* src = kb2 + ro * D_ + ss * 8;
        char* dst = ((char*)&Klds[p ^ 1][0]) + c * 4096 + w * 1024;
        __builtin_amdgcn_global_load_lds((const AS1 void*)src, (AS3 void*)dst, 16, 0, 0);
      }
      const unsigned short* v0 = vbase + (size_t)((kt + 1) * 32 + vk) * D_ + d0v;
      va = *(const ushort8*)v0; vb2 = *(const ushort8*)(v0 + D_);
    }

    if (kt <= kmy) {
      // ---- QK^T: S[16 q][32 k]
      f32x4 s[2];
#pragma unroll
      for (int ni = 0; ni < 2; ++ni) s[ni] = (f32x4){0.f, 0.f, 0.f, 0.f};
#pragma unroll
      for (int ks = 0; ks < 4; ++ks) {
#pragma unroll
        for (int ni = 0; ni < 2; ++ni) {
          const int row = ni * 16 + ll;
          const s16x8 kf = *(const s16x8*)&Klds[p][row * 128 + (((ks * 4 + lg) ^ (row & 7)) * 8)];
          s[ni] = __builtin_amdgcn_mfma_f32_16x16x32_bf16(qf[ks], kf, s[ni], 0, 0, 0);
        }
      }

      // ---- mask + defer-max softmax (log2 domain)
      const bool diag = (kt == kmy);
      float lm[4];
#pragma unroll
      for (int j = 0; j < 4; ++j) {
        if (diag) {
          const int qg = qr0 + lg * 4 + j;
#pragma unroll
          for (int ni = 0; ni < 2; ++ni)
            if (kt * 32 + ni * 16 + ll > qg) s[ni][j] = NEGBIG;
        }
        lm[j] = fmaxf(s[0][j], s[1][j]);
      }
      float excess = lm[0] - m_[0];
#pragma unroll
      for (int j = 1; j < 4; ++j) excess = fmaxf(excess, lm[j] - m_[j]);
      const bool slow = __any(excess > 11.5f);

#pragma unroll
      for (int j = 0; j < 4; ++j) {
        float p0, p1;
        if (slow) {
          float mt = lm[j];
          mt = fmaxf(mt, __shfl_xor(mt, 1));
          mt = fmaxf(mt, __shfl_xor(mt, 2));
          mt = fmaxf(mt, __shfl_xor(mt, 4));
          mt = fmaxf(mt, __shfl_xor(mt, 8));
          const float mnew = fmaxf(m_[j], mt);
          const float al = exp2f(m_[j] - mnew);
          m_[j] = mnew;
          p0 = exp2f(s[0][j] - mnew);
          p1 = exp2f(s[1][j] - mnew);
          l_[j] = l_[j] * al + p0 + p1;
#pragma unroll
          for (int nd = 0; nd < 8; ++nd) o[nd][j] *= al;
        } else {
          p0 = exp2f(s[0][j] - m_[j]);
          p1 = exp2f(s[1][j] - m_[j]);
          l_[j] += p0 + p1;
        }
        const int prow = lg * 4 + j;
        const int key = (prow >> 2) & 3;
        unsigned int u;
        asm("v_cvt_pk_bf16_f32 %0, %1, %2" : "=v"(u) : "v"(p0), "v"(p1));
        Ps[w][prow * 32 + (((ll >> 3) ^ key) * 8) + (ll & 7)] = (unsigned short)u;
        Ps[w][prow * 32 + ((((16 + ll) >> 3) ^ key) * 8) + (ll & 7)] = (unsigned short)(u >> 16);
      }

      // ---- PV: O += P[16x32] @ V[32x128]
      const s16x8 pa = *(const s16x8*)&Ps[w][ll * 32 + ((lg ^ ((ll >> 2) & 3)) * 8)];
#pragma unroll
      for (int nd = 0; nd < 8; ++nd) {
        const int vr = nd * 16 + ll;
        const s16x8 vbf = *(const s16x8*)&Vt[p][vr * 32 + ((lg ^ ((vr >> 2) & 3)) * 8)];
        o[nd] = __builtin_amdgcn_mfma_f32_16x16x32_bf16(pa, vbf, o[nd], 0, 0, 0);
      }
    }

    // ---- write next tile's V (regs -> LDS), single barrier
    if (kt < ktmax) {
#pragma unroll
      for (int j = 0; j < 8; ++j) {
        const int d = d0v + j;
        *(unsigned int*)&Vt[p ^ 1][d * 32 + (((vk >> 3) ^ ((d >> 2) & 3)) * 8) + (vk & 7)] =
            (unsigned int)va[j] | ((unsigned int)vb2[j] << 16);
      }
    }
    __syncthreads();
  }

  // ---- epilogue: reduce partial l over the 16-lane row group, store
#pragma unroll
  for (int j = 0; j < 4; ++j) {
    float ls = l_[j];
    ls += __shfl_xor(ls, 1);
    ls += __shfl_xor(ls, 2);
    ls += __shfl_xor(ls, 4);
    ls += __shfl_xor(ls, 8);
    const float inv = 1.f / ls;
    const size_t rowg = (size_t)b * S_ + qr0 + lg * 4 + j;
    unsigned short* op = &out[rowg * (NH_ * D_) + h * D_ + ll];
#pragma unroll
    for (int nd = 0; nd < 8; ++nd) op[nd * 16] = f2bf(o[nd][j] * inv);
  }
}

// ---------------------------------------------------------------------------
// Host launch
// ---------------------------------------------------------------------------
extern "C" void kernel_launch(void* const* d_in, const int* in_sizes, int n_in,
                              void* d_out, int out_size, void* d_ws, size_t ws_size,
                              hipStream_t stream) {
  const float* hidden = (const float*)d_in[0];
  const float* cosT   = (const float*)d_in[1];
  const float* sinT   = (const float*)d_in[2];
  const float* W_q    = (const float*)d_in[5];
  const float* W_k    = (const float*)d_in[6];
  const float* W_v    = (const float*)d_in[7];
  const float* W_o    = (const float*)d_in[8];
  const float* Vr     = (const float*)d_in[9];
  const float* Zv     = (const float*)d_in[10];
  float* out = (float*)d_out;

  // workspace map (bytes), peak 130,023,424 (verified fits)
  char* ws = (char*)d_ws;
  unsigned short* hb     = (unsigned short*)(ws + 0);           // 32MB hidden bf16 -> attn_b later
  unsigned short* attn_b = (unsigned short*)(ws + 0);
  unsigned short* q_b    = (unsigned short*)(ws + 33554432);    // 32MB (B,S,NH,D)
  unsigned short* kr_b   = (unsigned short*)(ws + 67108864);    // 32MB (B,NH,S,D)
  unsigned short* Wf     = (unsigned short*)(ws + 100663296);   // 1.5MB fused [384][2048] -> vh later
  unsigned short* vh_b   = (unsigned short*)(ws + 100663296);   // 16MB (B,NKV,S,D)
  unsigned short* WR1    = (unsigned short*)(ws + 117440512);   // 8MB Wq bf16 -> Wo bf16
  float*          pkpv   = (float*)(ws + 117440512);            // 12.6MB [M][384] f32

  const int M = B_ * S_;

  // 1) conversions + Q projection
  cvt_bf16<<<2048, 256, 0, stream>>>(hidden, hb, (B_ * S_ * HID_) / 8);
  cvt_bf16<<<2048, 256, 0, stream>>>(W_q, WR1, (HID_ * HID_) / 8);
  gemm_mfma<true><<<dim3(16, 64), 256, 0, stream>>>(hb, WR1, q_b, M, 2048, HID_);

  // 2) fused low-rank weights + direct pk|pv GEMM
  wfuse<<<dim3(24, 8), 256, 0, stream>>>(W_k, W_v, Vr, Zv, Wf);
  gemm_mfma<false><<<dim3(3, 64), 256, 0, stream>>>(hb, Wf, pkpv, M, 384, HID_);

  // 3) rope(q) in place
  rope_q<<<(B_ * S_ * NH_ * 64) / 256, 256, 0, stream>>>(q_b, cosT, sinT);

  // 4) expand K (+rope) and V
  expand_k<<<dim3(S_ / 32, NH_, B_), 256, 0, stream>>>(pkpv, Vr, cosT, sinT, kr_b);
  expand_v<<<dim3(S_ / 32, NKV_, B_), 256, 0, stream>>>(pkpv, Zv, vh_b);

  // 5) Wo conversion (pkpv dead after expanders)
  cvt_bf16<<<2048, 256, 0, stream>>>(W_o, WR1, (HID_ * HID_) / 8);

  // 6) attention (2048 blocks, 36KB LDS)
  attn_mfma<<<dim3(32, 16, 4), 256, 0, stream>>>(q_b, kr_b, vh_b, attn_b);

  // 7) output projection
  gemm_mfma<false><<<dim3(16, 64), 256, 0, stream>>>(attn_b, WR1, out, M, HID_, HID_);
}

// Round 10
// 778.863 us; speedup vs baseline: 1.2163x; 1.2163x over previous
//
#include <hip/hip_runtime.h>

typedef unsigned short ushort8 __attribute__((ext_vector_type(8)));
typedef short s16x8 __attribute__((ext_vector_type(8)));
typedef float f32x4 __attribute__((ext_vector_type(4)));

#define AS1 __attribute__((address_space(1)))
#define AS3 __attribute__((address_space(3)))

#define B_    4
#define S_    2048
#define HID_  2048
#define NH_   16
#define NKV_  8
#define D_    128
#define RK_   16
#define SCALING_ 0.08838834764831845f   // 128^-0.5
#define LOG2E_   1.4426950408889634f
#define NEGBIG   -1.0e30f

__device__ __forceinline__ float bf2f(unsigned short u) {
  union { unsigned int i; float f; } x; x.i = ((unsigned int)u) << 16; return x.f;
}
__device__ __forceinline__ unsigned short f2bf(float f) {
  union { float f; unsigned int i; } x; x.f = f;
  unsigned int r = x.i + 0x7fffu + ((x.i >> 16) & 1u);
  return (unsigned short)(r >> 16);
}

// ---------------------------------------------------------------------------
// f32 -> bf16 conversion, 8 elems/thread, grid-stride.
// ---------------------------------------------------------------------------
__global__ __launch_bounds__(256) void cvt_bf16(const float* __restrict__ in,
                                                unsigned short* __restrict__ out,
                                                int n8) {
  int i = blockIdx.x * 256 + threadIdx.x;
  const int stride = gridDim.x * 256;
  for (; i < n8; i += stride) {
    const float4 a = ((const float4*)in)[i * 2];
    const float4 b = ((const float4*)in)[i * 2 + 1];
    ushort8 u;
    u[0] = f2bf(a.x); u[1] = f2bf(a.y); u[2] = f2bf(a.z); u[3] = f2bf(a.w);
    u[4] = f2bf(b.x); u[5] = f2bf(b.y); u[6] = f2bf(b.z); u[7] = f2bf(b.w);
    *(ushort8*)&out[i * 8] = u;
  }
}

// ---------------------------------------------------------------------------
// Fused low-rank weights, bf16 out [384][2048]:
//   rows h*16+r       (h<16): Wkr = sum_d W_k[(h>>1)*128+d][c] * Vr[h][d][r]
//   rows 256+g*16+r   (g<8) : Wvz = sum_d W_v[g*128+d][c]      * Zv[g][d][r]
// ---------------------------------------------------------------------------
__global__ __launch_bounds__(256) void wfuse(const float* __restrict__ W_k,
                                             const float* __restrict__ W_v,
                                             const float* __restrict__ Vr,
                                             const float* __restrict__ Zv,
                                             unsigned short* __restrict__ Wf) {
  const int idx = blockIdx.x;
  const int cc = blockIdx.y * 256;
  const int tid = threadIdx.x;
  const bool isK = idx < 16;
  const int hg = isK ? idx : (idx - 16);
  const int wrow0 = isK ? (idx * 16) : (256 + (idx - 16) * 16);
  const float* W = isK ? &W_k[(size_t)((hg >> 1) * 128) * HID_]
                       : &W_v[(size_t)(hg * 128) * HID_];
  const float* P = isK ? &Vr[(size_t)hg * 128 * 16] : &Zv[(size_t)hg * 128 * 16];
  __shared__ float Wl[32][257];
  float acc[16] = {};
  for (int d0 = 0; d0 < 128; d0 += 32) {
    __syncthreads();
#pragma unroll 8
    for (int dd = 0; dd < 32; ++dd)
      Wl[dd][tid] = W[(size_t)(d0 + dd) * HID_ + cc + tid];
    __syncthreads();
#pragma unroll 8
    for (int dd = 0; dd < 32; ++dd) {
      const float w = Wl[dd][tid];
#pragma unroll
      for (int r = 0; r < 16; ++r) acc[r] += w * P[(d0 + dd) * 16 + r];
    }
  }
#pragma unroll
  for (int r = 0; r < 16; ++r)
    Wf[(size_t)(wrow0 + r) * HID_ + cc + tid] = f2bf(acc[r]);
}

// ---------------------------------------------------------------------------
// MFMA GEMM: C[M,N] = A[M,K] @ B[N,K]^T, A,B bf16, C f32 or bf16.
// 128x128 tile, BK=64, 4 waves, XCD chunk swizzle (grid blocks % 8 == 0).
// ---------------------------------------------------------------------------
template<bool CBF>
__global__ __launch_bounds__(256) void gemm_mfma(const unsigned short* __restrict__ A,
                                                 const unsigned short* __restrict__ Bb,
                                                 void* __restrict__ C_,
                                                 int M, int N, int K) {
  __shared__ unsigned short Ash[128 * 64];
  __shared__ unsigned short Bsh[128 * 64];
  const int tid = threadIdx.x;
  const int w = tid >> 6, l = tid & 63, lg = l >> 4, ll = l & 15;
  const int wr = w >> 1, wc = w & 1;
  const int flat = blockIdx.y * gridDim.x + blockIdx.x;
  const int cpx = (gridDim.x * gridDim.y) >> 3;
  const int swz = (flat & 7) * cpx + (flat >> 3);
  const int bm = (swz / gridDim.x) * 128, bn = (swz % gridDim.x) * 128;

  f32x4 acc[4][4];
#pragma unroll
  for (int i = 0; i < 4; i++)
#pragma unroll
    for (int j = 0; j < 4; j++) acc[i][j] = (f32x4){0.f, 0.f, 0.f, 0.f};

  const int srow = tid >> 3;
  const int sslot = tid & 7;

  for (int k0 = 0; k0 < K; k0 += 64) {
    __syncthreads();
#pragma unroll
    for (int c = 0; c < 4; ++c) {
      const int row = c * 32 + srow;
      const int ss = sslot ^ (row & 7);
      const unsigned short* srcA = &A[(size_t)(bm + row) * K + k0 + ss * 8];
      const unsigned short* srcB = &Bb[(size_t)(bn + row) * K + k0 + ss * 8];
      char* dstA = ((char*)Ash) + c * 4096 + w * 1024;
      char* dstB = ((char*)Bsh) + c * 4096 + w * 1024;
      __builtin_amdgcn_global_load_lds((const AS1 void*)srcA, (AS3 void*)dstA, 16, 0, 0);
      __builtin_amdgcn_global_load_lds((const AS1 void*)srcB, (AS3 void*)dstB, 16, 0, 0);
    }
    __syncthreads();

#pragma unroll
    for (int ks = 0; ks < 2; ++ks) {
      s16x8 af[4], bf_[4];
#pragma unroll
      for (int mi = 0; mi < 4; ++mi) {
        const int row = wr * 64 + mi * 16 + ll;
        af[mi] = *(const s16x8*)&Ash[row * 64 + (((ks * 4 + lg) ^ (row & 7)) * 8)];
      }
#pragma unroll
      for (int ni = 0; ni < 4; ++ni) {
        const int row = wc * 64 + ni * 16 + ll;
        bf_[ni] = *(const s16x8*)&Bsh[row * 64 + (((ks * 4 + lg) ^ (row & 7)) * 8)];
      }
#pragma unroll
      for (int mi = 0; mi < 4; ++mi)
#pragma unroll
        for (int ni = 0; ni < 4; ++ni)
          acc[mi][ni] = __builtin_amdgcn_mfma_f32_16x16x32_bf16(af[mi], bf_[ni], acc[mi][ni], 0, 0, 0);
    }
  }

#pragma unroll
  for (int mi = 0; mi < 4; ++mi)
#pragma unroll
    for (int ni = 0; ni < 4; ++ni)
#pragma unroll
      for (int j = 0; j < 4; ++j) {
        const int row = bm + wr * 64 + mi * 16 + lg * 4 + j;
        const int col = bn + wc * 64 + ni * 16 + ll;
        if (CBF) ((unsigned short*)C_)[(size_t)row * N + col] = f2bf(acc[mi][ni][j]);
        else     ((float*)C_)[(size_t)row * N + col] = acc[mi][ni][j];
      }
}

// ---------------------------------------------------------------------------
// In-place RoPE on bf16 q, folding SCALING*log2(e).
// ---------------------------------------------------------------------------
__global__ __launch_bounds__(256) void rope_q(unsigned short* __restrict__ q,
                                              const float* __restrict__ cosT,
                                              const float* __restrict__ sinT) {
  const int p = blockIdx.x * 256 + threadIdx.x;
  const int d = p & 63;
  const int h = (p >> 6) & 15;
  const int s = (p >> 10) & 2047;
  const int b = p >> 21;
  const size_t base = (((size_t)b * S_ + s) * NH_ + h) * D_ + d;
  const float x1 = bf2f(q[base]), x2 = bf2f(q[base + 64]);
  const float c = cosT[s * 64 + d], sn = sinT[s * 64 + d];
  const float sc = SCALING_ * LOG2E_;
  q[base]      = f2bf((x1 * c - x2 * sn) * sc);
  q[base + 64] = f2bf((x1 * sn + x2 * c) * sc);
}

// ---------------------------------------------------------------------------
// Expand pk (fused [M][384] f32, cols h*16+r) -> k_rot bf16 (B,NH,S,D) +RoPE.
// ---------------------------------------------------------------------------
__global__ __launch_bounds__(256) void expand_k(const float* __restrict__ pkpv,
                                                const float* __restrict__ Vr,
                                                const float* __restrict__ cosT,
                                                const float* __restrict__ sinT,
                                                unsigned short* __restrict__ kr) {
  const int s0 = blockIdx.x * 32, h = blockIdx.y, b = blockIdx.z;
  const int tid = threadIdx.x;
  __shared__ float pkS[32][17];
  if (tid < 128) {
    const int r_ = tid >> 2, c4 = (tid & 3) * 4;
    float4 v = *(const float4*)&pkpv[(size_t)(b * S_ + s0 + r_) * 384 + h * 16 + c4];
    pkS[r_][c4 + 0] = v.x; pkS[r_][c4 + 1] = v.y;
    pkS[r_][c4 + 2] = v.z; pkS[r_][c4 + 3] = v.w;
  }
  __syncthreads();
  const int row = tid >> 3, dl = tid & 7;
  float kh[16];
#pragma unroll
  for (int j = 0; j < 16; j++) {
    const int d = dl + 8 * j;
    const float4* w = (const float4*)&Vr[((size_t)h * D_ + d) * RK_];
    float a = 0.f;
#pragma unroll
    for (int q4 = 0; q4 < 4; q4++) {
      float4 wv = w[q4];
      a += pkS[row][q4 * 4 + 0] * wv.x + pkS[row][q4 * 4 + 1] * wv.y
         + pkS[row][q4 * 4 + 2] * wv.z + pkS[row][q4 * 4 + 3] * wv.w;
    }
    kh[j] = a;
  }
  const int pos = s0 + row;
  const size_t o = (((size_t)b * NH_ + h) * S_ + pos) * D_;
#pragma unroll
  for (int j = 0; j < 8; j++) {
    const int d = dl + 8 * j;
    const float c = cosT[pos * 64 + d], sn = sinT[pos * 64 + d];
    kr[o + d]      = f2bf(kh[j] * c - kh[j + 8] * sn);
    kr[o + d + 64] = f2bf(kh[j] * sn + kh[j + 8] * c);
  }
}

// ---------------------------------------------------------------------------
// Expand pv (cols 256+g*16+r) -> v_hat bf16 (B,NKV,S,D).
// ---------------------------------------------------------------------------
__global__ __launch_bounds__(256) void expand_v(const float* __restrict__ pkpv,
                                                const float* __restrict__ Zv,
                                                unsigned short* __restrict__ vh) {
  const int s0 = blockIdx.x * 32, g = blockIdx.y, b = blockIdx.z;
  const int tid = threadIdx.x;
  __shared__ float pvS[32][17];
  if (tid < 128) {
    const int r_ = tid >> 2, c4 = (tid & 3) * 4;
    float4 v = *(const float4*)&pkpv[(size_t)(b * S_ + s0 + r_) * 384 + 256 + g * 16 + c4];
    pvS[r_][c4 + 0] = v.x; pvS[r_][c4 + 1] = v.y;
    pvS[r_][c4 + 2] = v.z; pvS[r_][c4 + 3] = v.w;
  }
  __syncthreads();
  const int row = tid >> 3, dl = tid & 7;
  const size_t o = (((size_t)b * NKV_ + g) * S_ + s0 + row) * D_;
#pragma unroll
  for (int j = 0; j < 16; j++) {
    const int d = dl + 8 * j;
    const float4* w = (const float4*)&Zv[((size_t)g * D_ + d) * RK_];
    float a = 0.f;
#pragma unroll
    for (int q4 = 0; q4 < 4; q4++) {
      float4 wv = w[q4];
      a += pvS[row][q4 * 4 + 0] * wv.x + pvS[row][q4 * 4 + 1] * wv.y
         + pvS[row][q4 * 4 + 2] * wv.z + pvS[row][q4 * 4 + 3] * wv.w;
    }
    vh[o + d] = f2bf(a);
  }
}

// ---------------------------------------------------------------------------
// MFMA flash attention v5 = round-8 structure with P stored in the dead
// current-K buffer (Klds[p] is fully read by end of QK^T; staging for t+2
// only writes it after the end-of-tile barrier). Saves the 16KB Ps buffer:
// LDS 80 -> 64KB so TWO blocks/CU co-reside (round-8's 2x80=160KB exact fit
// measured ~1 block/CU, 8.6% occupancy). Costs one extra mid-tile barrier.
// 256 thr = 4 waves x 32 q-rows, KVBLK 64, dbuf K via global_load_lds,
// reg-staged V write-late, defer-max log2 softmax, cvt_pk P-pack. VGPR ~224
// (natural; rounds 5/6: capping spills).
// ---------------------------------------------------------------------------
__global__ __launch_bounds__(256) void attn_mfma(const unsigned short* __restrict__ q,
                                                 const unsigned short* __restrict__ kr,
                                                 const unsigned short* __restrict__ vh,
                                                 unsigned short* __restrict__ out) {
  const int flat = ((int)blockIdx.z * 16 + (int)blockIdx.y) * 16 + (int)blockIdx.x;
  const int swz = (flat & 7) * 128 + (flat >> 3);   // XCD chunking
  const int qt = 15 - (swz & 15);                   // big q-tiles first
  const int h = (swz >> 4) & 15;
  const int b = swz >> 8;
  const int g = h >> 1;
  const int tid = threadIdx.x;
  const int w = tid >> 6, l = tid & 63, lg = l >> 4, ll = l & 15;

  __shared__ unsigned short Klds[2][64 * 128];  // K tiles; P reuses Klds[p] quarter per wave
  __shared__ unsigned short Vt[2][128 * 64];    // transposed V

  const int qr0 = qt * 128 + w * 32;
  const int ktmax = 2 * qt + 1;
  const int kmy = 2 * qt + (w >> 1);

  s16x8 qf[2][4];
#pragma unroll
  for (int mi = 0; mi < 2; ++mi)
#pragma unroll
    for (int ks = 0; ks < 4; ++ks)
      qf[mi][ks] = *(const s16x8*)&q[(((size_t)b * S_ + qr0 + mi * 16 + ll) * NH_ + h) * D_ + ks * 32 + lg * 8];

  f32x4 o[2][8];
#pragma unroll
  for (int mi = 0; mi < 2; ++mi)
#pragma unroll
    for (int nd = 0; nd < 8; ++nd) o[mi][nd] = (f32x4){0.f, 0.f, 0.f, 0.f};
  float m_[2][4], l_[2][4];
#pragma unroll
  for (int mi = 0; mi < 2; ++mi)
#pragma unroll
    for (int j = 0; j < 4; ++j) { m_[mi][j] = NEGBIG; l_[mi][j] = 0.f; }

  const unsigned short* kbase = &kr[(((size_t)b * NH_ + h) * S_) * D_];
  const unsigned short* vbase = &vh[(((size_t)b * NKV_ + g) * S_) * D_];
  const int vk = (tid & 31) * 2, d0v = (tid >> 5) * 16;

  ushort8 va0, va1, vb0, vb1;
  {
#pragma unroll
    for (int c = 0; c < 4; ++c) {
      const int ro = c * 16 + w * 4 + lg;
      const int ss = ll ^ (ro & 7);
      const unsigned short* src = kbase + ro * D_ + ss * 8;
      char* dst = ((char*)&Klds[0][0]) + c * 4096 + w * 1024;
      __builtin_amdgcn_global_load_lds((const AS1 void*)src, (AS3 void*)dst, 16, 0, 0);
    }
    const unsigned short* v0 = vbase + (size_t)vk * D_ + d0v;
    va0 = *(const ushort8*)v0; va1 = *(const ushort8*)(v0 + 8);
    vb0 = *(const ushort8*)(v0 + D_); vb1 = *(const ushort8*)(v0 + D_ + 8);
#pragma unroll
    for (int j = 0; j < 8; ++j) {
      const int d1 = d0v + j, d2 = d0v + 8 + j;
      *(unsigned int*)&Vt[0][d1 * 64 + (((vk >> 3) ^ (d1 & 7)) * 8) + (vk & 7)] =
          (unsigned int)va0[j] | ((unsigned int)vb0[j] << 16);
      *(unsigned int*)&Vt[0][d2 * 64 + (((vk >> 3) ^ (d2 & 7)) * 8) + (vk & 7)] =
          (unsigned int)va1[j] | ((unsigned int)vb1[j] << 16);
    }
  }
  __syncthreads();

  for (int kt = 0; kt <= ktmax; ++kt) {
    const int p = kt & 1;
    // ---- issue next-tile staging (K direct to LDS[p^1], V to regs)
    if (kt < ktmax) {
      const unsigned short* kb2 = kbase + (size_t)(kt + 1) * 64 * D_;
#pragma unroll
      for (int c = 0; c < 4; ++c) {
        const int ro = c * 16 + w * 4 + lg;
        const int ss = ll ^ (ro & 7);
        const unsigned short* src = kb2 + ro * D_ + ss * 8;
        char* dst = ((char*)&Klds[p ^ 1][0]) + c * 4096 + w * 1024;
        __builtin_amdgcn_global_load_lds((const AS1 void*)src, (AS3 void*)dst, 16, 0, 0);
      }
      const unsigned short* v0 = vbase + (size_t)((kt + 1) * 64 + vk) * D_ + d0v;
      va0 = *(const ushort8*)v0; va1 = *(const ushort8*)(v0 + 8);
      vb0 = *(const ushort8*)(v0 + D_); vb1 = *(const ushort8*)(v0 + D_ + 8);
    }

    if (kt <= kmy) {
      // ---- QK^T: S[32 q][64 k] from Klds[p]
      f32x4 s[2][4];
#pragma unroll
      for (int mi = 0; mi < 2; ++mi)
#pragma unroll
        for (int ni = 0; ni < 4; ++ni) s[mi][ni] = (f32x4){0.f, 0.f, 0.f, 0.f};
#pragma unroll
      for (int ks = 0; ks < 4; ++ks) {
#pragma unroll
        for (int ni = 0; ni < 4; ++ni) {
          const int row = ni * 16 + ll;
          const s16x8 kf = *(const s16x8*)&Klds[p][row * 128 + (((ks * 4 + lg) ^ (row & 7)) * 8)];
          s[0][ni] = __builtin_amdgcn_mfma_f32_16x16x32_bf16(qf[0][ks], kf, s[0][ni], 0, 0, 0);
          s[1][ni] = __builtin_amdgcn_mfma_f32_16x16x32_bf16(qf[1][ks], kf, s[1][ni], 0, 0, 0);
        }
      }
      // all waves done reading K(t) -> its buffer becomes the P scratch
      __syncthreads();
      unsigned short* Pw = &Klds[p][w * 2048];   // 32 rows x 64 cols per wave

      // ---- mask + defer-max softmax (log2 domain)
      const bool diag = (kt == kmy);
      float lm[2][4];
#pragma unroll
      for (int mi = 0; mi < 2; ++mi)
#pragma unroll
        for (int j = 0; j < 4; ++j) {
          if (diag) {
            const int qg = qr0 + mi * 16 + lg * 4 + j;
#pragma unroll
            for (int ni = 0; ni < 4; ++ni)
              if (kt * 64 + ni * 16 + ll > qg) s[mi][ni][j] = NEGBIG;
          }
          lm[mi][j] = fmaxf(fmaxf(s[mi][0][j], s[mi][1][j]),
                            fmaxf(s[mi][2][j], s[mi][3][j]));
        }
      float excess = lm[0][0] - m_[0][0];
#pragma unroll
      for (int mi = 0; mi < 2; ++mi)
#pragma unroll
        for (int j = 0; j < 4; ++j) excess = fmaxf(excess, lm[mi][j] - m_[mi][j]);
      const bool slow = __any(excess > 11.5f);

#pragma unroll
      for (int mi = 0; mi < 2; ++mi)
#pragma unroll
        for (int j = 0; j < 4; ++j) {
          float ps_[4];
          if (slow) {
            float mt = lm[mi][j];
            mt = fmaxf(mt, __shfl_xor(mt, 1));
            mt = fmaxf(mt, __shfl_xor(mt, 2));
            mt = fmaxf(mt, __shfl_xor(mt, 4));
            mt = fmaxf(mt, __shfl_xor(mt, 8));
            const float mnew = fmaxf(m_[mi][j], mt);
            const float al = exp2f(m_[mi][j] - mnew);
            m_[mi][j] = mnew;
            float sum = 0.f;
#pragma unroll
            for (int ni = 0; ni < 4; ++ni) { ps_[ni] = exp2f(s[mi][ni][j] - mnew); sum += ps_[ni]; }
            l_[mi][j] = l_[mi][j] * al + sum;
#pragma unroll
            for (int nd = 0; nd < 8; ++nd) o[mi][nd][j] *= al;
          } else {
            float sum = 0.f;
#pragma unroll
            for (int ni = 0; ni < 4; ++ni) { ps_[ni] = exp2f(s[mi][ni][j] - m_[mi][j]); sum += ps_[ni]; }
            l_[mi][j] += sum;
          }
          const int prow = mi * 16 + lg * 4 + j;
#pragma unroll
          for (int nq = 0; nq < 2; ++nq) {
            unsigned int u;
            asm("v_cvt_pk_bf16_f32 %0, %1, %2" : "=v"(u) : "v"(ps_[nq * 2]), "v"(ps_[nq * 2 + 1]));
            const int c0 = nq * 32 + ll, c1 = nq * 32 + 16 + ll;
            Pw[prow * 64 + (((c0 >> 3) ^ (prow & 7)) * 8) + (ll & 7)] = (unsigned short)u;
            Pw[prow * 64 + (((c1 >> 3) ^ (prow & 7)) * 8) + (ll & 7)] = (unsigned short)(u >> 16);
          }
        }

      // ---- PV: O += P[32x64] @ V[64x128] (P from own quarter, same-wave DS order)
      s16x8 pa[2][2];
#pragma unroll
      for (int mi = 0; mi < 2; ++mi)
#pragma unroll
        for (int ks2 = 0; ks2 < 2; ++ks2) {
          const int prow = mi * 16 + ll;
          pa[mi][ks2] = *(const s16x8*)&Pw[prow * 64 + (((ks2 * 4 + lg) ^ (prow & 7)) * 8)];
        }
#pragma unroll
      for (int nd = 0; nd < 8; ++nd) {
#pragma unroll
        for (int ks2 = 0; ks2 < 2; ++ks2) {
          const int vr = nd * 16 + ll;
          const s16x8 vbf = *(const s16x8*)&Vt[p][vr * 64 + (((ks2 * 4 + lg) ^ (vr & 7)) * 8)];
          o[0][nd] = __builtin_amdgcn_mfma_f32_16x16x32_bf16(pa[0][ks2], vbf, o[0][nd], 0, 0, 0);
          o[1][nd] = __builtin_amdgcn_mfma_f32_16x16x32_bf16(pa[1][ks2], vbf, o[1][nd], 0, 0, 0);
        }
      }
    } else {
      // keep barrier count identical across waves in the block
      __syncthreads();
    }

    // ---- write next tile's V (regs -> LDS[p^1]), end-of-tile barrier
    if (kt < ktmax) {
#pragma unroll
      for (int j = 0; j < 8; ++j) {
        const int d1 = d0v + j, d2 = d0v + 8 + j;
        *(unsigned int*)&Vt[p ^ 1][d1 * 64 + (((vk >> 3) ^ (d1 & 7)) * 8) + (vk & 7)] =
            (unsigned int)va0[j] | ((unsigned int)vb0[j] << 16);
        *(unsigned int*)&Vt[p ^ 1][d2 * 64 + (((vk >> 3) ^ (d2 & 7)) * 8) + (vk & 7)] =
            (unsigned int)va1[j] | ((unsigned int)vb1[j] << 16);
      }
    }
    __syncthreads();
  }

#pragma unroll
  for (int mi = 0; mi < 2; ++mi)
#pragma unroll
    for (int j = 0; j < 4; ++j) {
      float ls = l_[mi][j];
      ls += __shfl_xor(ls, 1);
      ls += __shfl_xor(ls, 2);
      ls += __shfl_xor(ls, 4);
      ls += __shfl_xor(ls, 8);
      const float inv = 1.f / ls;
      const size_t rowg = (size_t)b * S_ + qr0 + mi * 16 + lg * 4 + j;
      unsigned short* op = &out[rowg * (NH_ * D_) + h * D_ + ll];
#pragma unroll
      for (int nd = 0; nd < 8; ++nd) op[nd * 16] = f2bf(o[mi][nd][j] * inv);
    }
}

// ---------------------------------------------------------------------------
// Host launch
// ---------------------------------------------------------------------------
extern "C" void kernel_launch(void* const* d_in, const int* in_sizes, int n_in,
                              void* d_out, int out_size, void* d_ws, size_t ws_size,
                              hipStream_t stream) {
  const float* hidden = (const float*)d_in[0];
  const float* cosT   = (const float*)d_in[1];
  const float* sinT   = (const float*)d_in[2];
  const float* W_q    = (const float*)d_in[5];
  const float* W_k    = (const float*)d_in[6];
  const float* W_v    = (const float*)d_in[7];
  const float* W_o    = (const float*)d_in[8];
  const float* Vr     = (const float*)d_in[9];
  const float* Zv     = (const float*)d_in[10];
  float* out = (float*)d_out;

  // workspace map (bytes), peak 130,023,424 (verified fits)
  char* ws = (char*)d_ws;
  unsigned short* hb     = (unsigned short*)(ws + 0);           // 32MB hidden bf16 -> attn_b later
  unsigned short* attn_b = (unsigned short*)(ws + 0);
  unsigned short* q_b    = (unsigned short*)(ws + 33554432);    // 32MB (B,S,NH,D)
  unsigned short* kr_b   = (unsigned short*)(ws + 67108864);    // 32MB (B,NH,S,D)
  unsigned short* Wf     = (unsigned short*)(ws + 100663296);   // 1.5MB fused [384][2048] -> vh later
  unsigned short* vh_b   = (unsigned short*)(ws + 100663296);   // 16MB (B,NKV,S,D)
  unsigned short* WR1    = (unsigned short*)(ws + 117440512);   // 8MB Wq bf16 -> Wo bf16
  float*          pkpv   = (float*)(ws + 117440512);            // 12.6MB [M][384] f32

  const int M = B_ * S_;

  // 1) conversions + Q projection
  cvt_bf16<<<2048, 256, 0, stream>>>(hidden, hb, (B_ * S_ * HID_) / 8);
  cvt_bf16<<<2048, 256, 0, stream>>>(W_q, WR1, (HID_ * HID_) / 8);
  gemm_mfma<true><<<dim3(16, 64), 256, 0, stream>>>(hb, WR1, q_b, M, 2048, HID_);

  // 2) fused low-rank weights + direct pk|pv GEMM
  wfuse<<<dim3(24, 8), 256, 0, stream>>>(W_k, W_v, Vr, Zv, Wf);
  gemm_mfma<false><<<dim3(3, 64), 256, 0, stream>>>(hb, Wf, pkpv, M, 384, HID_);

  // 3) rope(q) in place
  rope_q<<<(B_ * S_ * NH_ * 64) / 256, 256, 0, stream>>>(q_b, cosT, sinT);

  // 4) expand K (+rope) and V
  expand_k<<<dim3(S_ / 32, NH_, B_), 256, 0, stream>>>(pkpv, Vr, cosT, sinT, kr_b);
  expand_v<<<dim3(S_ / 32, NKV_, B_), 256, 0, stream>>>(pkpv, Zv, vh_b);

  // 5) Wo conversion (pkpv dead after expanders)
  cvt_bf16<<<2048, 256, 0, stream>>>(W_o, WR1, (HID_ * HID_) / 8);

  // 6) attention (64KB LDS -> 2 blocks/CU)
  attn_mfma<<<dim3(16, 16, 4), 256, 0, stream>>>(q_b, kr_b, vh_b, attn_b);

  // 7) output projection
  gemm_mfma<false><<<dim3(16, 64), 256, 0, stream>>>(attn_b, WR1, out, M, HID_, HID_);
}

// Round 11
// 746.955 us; speedup vs baseline: 1.2683x; 1.0427x over previous
//
#include <hip/hip_runtime.h>

typedef unsigned short ushort8 __attribute__((ext_vector_type(8)));
typedef short s16x8 __attribute__((ext_vector_type(8)));
typedef float f32x4 __attribute__((ext_vector_type(4)));

#define AS1 __attribute__((address_space(1)))
#define AS3 __attribute__((address_space(3)))

#define B_    4
#define S_    2048
#define HID_  2048
#define NH_   16
#define NKV_  8
#define D_    128
#define RK_   16
#define SCALING_ 0.08838834764831845f   // 128^-0.5
#define LOG2E_   1.4426950408889634f
#define NEGBIG   -1.0e30f

__device__ __forceinline__ float bf2f(unsigned short u) {
  union { unsigned int i; float f; } x; x.i = ((unsigned int)u) << 16; return x.f;
}
__device__ __forceinline__ unsigned short f2bf(float f) {
  union { float f; unsigned int i; } x; x.f = f;
  unsigned int r = x.i + 0x7fffu + ((x.i >> 16) & 1u);
  return (unsigned short)(r >> 16);
}

// ---------------------------------------------------------------------------
// f32 -> bf16 conversion, 8 elems/thread, grid-stride.
// ---------------------------------------------------------------------------
__global__ __launch_bounds__(256) void cvt_bf16(const float* __restrict__ in,
                                                unsigned short* __restrict__ out,
                                                int n8) {
  int i = blockIdx.x * 256 + threadIdx.x;
  const int stride = gridDim.x * 256;
  for (; i < n8; i += stride) {
    const float4 a = ((const float4*)in)[i * 2];
    const float4 b = ((const float4*)in)[i * 2 + 1];
    ushort8 u;
    u[0] = f2bf(a.x); u[1] = f2bf(a.y); u[2] = f2bf(a.z); u[3] = f2bf(a.w);
    u[4] = f2bf(b.x); u[5] = f2bf(b.y); u[6] = f2bf(b.z); u[7] = f2bf(b.w);
    *(ushort8*)&out[i * 8] = u;
  }
}

// ---------------------------------------------------------------------------
// Fused low-rank weights, bf16 out [384][2048].
// ---------------------------------------------------------------------------
__global__ __launch_bounds__(256) void wfuse(const float* __restrict__ W_k,
                                             const float* __restrict__ W_v,
                                             const float* __restrict__ Vr,
                                             const float* __restrict__ Zv,
                                             unsigned short* __restrict__ Wf) {
  const int idx = blockIdx.x;
  const int cc = blockIdx.y * 256;
  const int tid = threadIdx.x;
  const bool isK = idx < 16;
  const int hg = isK ? idx : (idx - 16);
  const int wrow0 = isK ? (idx * 16) : (256 + (idx - 16) * 16);
  const float* W = isK ? &W_k[(size_t)((hg >> 1) * 128) * HID_]
                       : &W_v[(size_t)(hg * 128) * HID_];
  const float* P = isK ? &Vr[(size_t)hg * 128 * 16] : &Zv[(size_t)hg * 128 * 16];
  __shared__ float Wl[32][257];
  float acc[16] = {};
  for (int d0 = 0; d0 < 128; d0 += 32) {
    __syncthreads();
#pragma unroll 8
    for (int dd = 0; dd < 32; ++dd)
      Wl[dd][tid] = W[(size_t)(d0 + dd) * HID_ + cc + tid];
    __syncthreads();
#pragma unroll 8
    for (int dd = 0; dd < 32; ++dd) {
      const float w = Wl[dd][tid];
#pragma unroll
      for (int r = 0; r < 16; ++r) acc[r] += w * P[(d0 + dd) * 16 + r];
    }
  }
#pragma unroll
  for (int r = 0; r < 16; ++r)
    Wf[(size_t)(wrow0 + r) * HID_ + cc + tid] = f2bf(acc[r]);
}

// ---------------------------------------------------------------------------
// MFMA GEMM: C[M,N] = A[M,K] @ B[N,K]^T, A,B bf16, C f32 or bf16.
// ---------------------------------------------------------------------------
template<bool CBF>
__global__ __launch_bounds__(256) void gemm_mfma(const unsigned short* __restrict__ A,
                                                 const unsigned short* __restrict__ Bb,
                                                 void* __restrict__ C_,
                                                 int M, int N, int K) {
  __shared__ unsigned short Ash[128 * 64];
  __shared__ unsigned short Bsh[128 * 64];
  const int tid = threadIdx.x;
  const int w = tid >> 6, l = tid & 63, lg = l >> 4, ll = l & 15;
  const int wr = w >> 1, wc = w & 1;
  const int flat = blockIdx.y * gridDim.x + blockIdx.x;
  const int cpx = (gridDim.x * gridDim.y) >> 3;
  const int swz = (flat & 7) * cpx + (flat >> 3);
  const int bm = (swz / gridDim.x) * 128, bn = (swz % gridDim.x) * 128;

  f32x4 acc[4][4];
#pragma unroll
  for (int i = 0; i < 4; i++)
#pragma unroll
    for (int j = 0; j < 4; j++) acc[i][j] = (f32x4){0.f, 0.f, 0.f, 0.f};

  const int srow = tid >> 3;
  const int sslot = tid & 7;

  for (int k0 = 0; k0 < K; k0 += 64) {
    __syncthreads();
#pragma unroll
    for (int c = 0; c < 4; ++c) {
      const int row = c * 32 + srow;
      const int ss = sslot ^ (row & 7);
      const unsigned short* srcA = &A[(size_t)(bm + row) * K + k0 + ss * 8];
      const unsigned short* srcB = &Bb[(size_t)(bn + row) * K + k0 + ss * 8];
      char* dstA = ((char*)Ash) + c * 4096 + w * 1024;
      char* dstB = ((char*)Bsh) + c * 4096 + w * 1024;
      __builtin_amdgcn_global_load_lds((const AS1 void*)srcA, (AS3 void*)dstA, 16, 0, 0);
      __builtin_amdgcn_global_load_lds((const AS1 void*)srcB, (AS3 void*)dstB, 16, 0, 0);
    }
    __syncthreads();

#pragma unroll
    for (int ks = 0; ks < 2; ++ks) {
      s16x8 af[4], bf_[4];
#pragma unroll
      for (int mi = 0; mi < 4; ++mi) {
        const int row = wr * 64 + mi * 16 + ll;
        af[mi] = *(const s16x8*)&Ash[row * 64 + (((ks * 4 + lg) ^ (row & 7)) * 8)];
      }
#pragma unroll
      for (int ni = 0; ni < 4; ++ni) {
        const int row = wc * 64 + ni * 16 + ll;
        bf_[ni] = *(const s16x8*)&Bsh[row * 64 + (((ks * 4 + lg) ^ (row & 7)) * 8)];
      }
#pragma unroll
      for (int mi = 0; mi < 4; ++mi)
#pragma unroll
        for (int ni = 0; ni < 4; ++ni)
          acc[mi][ni] = __builtin_amdgcn_mfma_f32_16x16x32_bf16(af[mi], bf_[ni], acc[mi][ni], 0, 0, 0);
    }
  }

#pragma unroll
  for (int mi = 0; mi < 4; ++mi)
#pragma unroll
    for (int ni = 0; ni < 4; ++ni)
#pragma unroll
      for (int j = 0; j < 4; ++j) {
        const int row = bm + wr * 64 + mi * 16 + lg * 4 + j;
        const int col = bn + wc * 64 + ni * 16 + ll;
        if (CBF) ((unsigned short*)C_)[(size_t)row * N + col] = f2bf(acc[mi][ni][j]);
        else     ((float*)C_)[(size_t)row * N + col] = acc[mi][ni][j];
      }
}

// ---------------------------------------------------------------------------
// In-place RoPE on bf16 q, folding SCALING*log2(e).
// ---------------------------------------------------------------------------
__global__ __launch_bounds__(256) void rope_q(unsigned short* __restrict__ q,
                                              const float* __restrict__ cosT,
                                              const float* __restrict__ sinT) {
  const int p = blockIdx.x * 256 + threadIdx.x;
  const int d = p & 63;
  const int h = (p >> 6) & 15;
  const int s = (p >> 10) & 2047;
  const int b = p >> 21;
  const size_t base = (((size_t)b * S_ + s) * NH_ + h) * D_ + d;
  const float x1 = bf2f(q[base]), x2 = bf2f(q[base + 64]);
  const float c = cosT[s * 64 + d], sn = sinT[s * 64 + d];
  const float sc = SCALING_ * LOG2E_;
  q[base]      = f2bf((x1 * c - x2 * sn) * sc);
  q[base + 64] = f2bf((x1 * sn + x2 * c) * sc);
}

// ---------------------------------------------------------------------------
// Expand pk (fused [M][384] f32, cols h*16+r) -> k_rot bf16 (B,NH,S,D) +RoPE.
// ---------------------------------------------------------------------------
__global__ __launch_bounds__(256) void expand_k(const float* __restrict__ pkpv,
                                                const float* __restrict__ Vr,
                                                const float* __restrict__ cosT,
                                                const float* __restrict__ sinT,
                                                unsigned short* __restrict__ kr) {
  const int s0 = blockIdx.x * 32, h = blockIdx.y, b = blockIdx.z;
  const int tid = threadIdx.x;
  __shared__ float pkS[32][17];
  if (tid < 128) {
    const int r_ = tid >> 2, c4 = (tid & 3) * 4;
    float4 v = *(const float4*)&pkpv[(size_t)(b * S_ + s0 + r_) * 384 + h * 16 + c4];
    pkS[r_][c4 + 0] = v.x; pkS[r_][c4 + 1] = v.y;
    pkS[r_][c4 + 2] = v.z; pkS[r_][c4 + 3] = v.w;
  }
  __syncthreads();
  const int row = tid >> 3, dl = tid & 7;
  float kh[16];
#pragma unroll
  for (int j = 0; j < 16; j++) {
    const int d = dl + 8 * j;
    const float4* w = (const float4*)&Vr[((size_t)h * D_ + d) * RK_];
    float a = 0.f;
#pragma unroll
    for (int q4 = 0; q4 < 4; q4++) {
      float4 wv = w[q4];
      a += pkS[row][q4 * 4 + 0] * wv.x + pkS[row][q4 * 4 + 1] * wv.y
         + pkS[row][q4 * 4 + 2] * wv.z + pkS[row][q4 * 4 + 3] * wv.w;
    }
    kh[j] = a;
  }
  const int pos = s0 + row;
  const size_t o = (((size_t)b * NH_ + h) * S_ + pos) * D_;
#pragma unroll
  for (int j = 0; j < 8; j++) {
    const int d = dl + 8 * j;
    const float c = cosT[pos * 64 + d], sn = sinT[pos * 64 + d];
    kr[o + d]      = f2bf(kh[j] * c - kh[j + 8] * sn);
    kr[o + d + 64] = f2bf(kh[j] * sn + kh[j + 8] * c);
  }
}

// ---------------------------------------------------------------------------
// Expand pv (cols 256+g*16+r) -> v_hat bf16 (B,NKV,S,D).
// ---------------------------------------------------------------------------
__global__ __launch_bounds__(256) void expand_v(const float* __restrict__ pkpv,
                                                const float* __restrict__ Zv,
                                                unsigned short* __restrict__ vh) {
  const int s0 = blockIdx.x * 32, g = blockIdx.y, b = blockIdx.z;
  const int tid = threadIdx.x;
  __shared__ float pvS[32][17];
  if (tid < 128) {
    const int r_ = tid >> 2, c4 = (tid & 3) * 4;
    float4 v = *(const float4*)&pkpv[(size_t)(b * S_ + s0 + r_) * 384 + 256 + g * 16 + c4];
    pvS[r_][c4 + 0] = v.x; pvS[r_][c4 + 1] = v.y;
    pvS[r_][c4 + 2] = v.z; pvS[r_][c4 + 3] = v.w;
  }
  __syncthreads();
  const int row = tid >> 3, dl = tid & 7;
  const size_t o = (((size_t)b * NKV_ + g) * S_ + s0 + row) * D_;
#pragma unroll
  for (int j = 0; j < 16; j++) {
    const int d = dl + 8 * j;
    const float4* w = (const float4*)&Zv[((size_t)g * D_ + d) * RK_];
    float a = 0.f;
#pragma unroll
    for (int q4 = 0; q4 < 4; q4++) {
      float4 wv = w[q4];
      a += pvS[row][q4 * 4 + 0] * wv.x + pvS[row][q4 * 4 + 1] * wv.y
         + pvS[row][q4 * 4 + 2] * wv.z + pvS[row][q4 * 4 + 3] * wv.w;
    }
    vh[o + d] = f2bf(a);
  }
}

// ---------------------------------------------------------------------------
// MFMA flash attention, round-8 inner structure (proven 398us), templated on
// SPLIT. SPLIT=1: each (b,h,qt) runs as TWO equal-work blocks (KV tiles
// [0,qt] / [qt+1,2qt+1]) writing unnormalized O~ (bf16) + per-row (m,l) f32;
// combine kernel merges. SPLIT=0: round-8 behavior (normalize, write attn_b).
// ---------------------------------------------------------------------------
template<bool SPLIT>
__global__ __launch_bounds__(256) void attn_mfma(const unsigned short* __restrict__ q,
                                                 const unsigned short* __restrict__ kr,
                                                 const unsigned short* __restrict__ vh,
                                                 unsigned short* __restrict__ outp,
                                                 unsigned short* __restrict__ P0,
                                                 unsigned short* __restrict__ P1,
                                                 float2* __restrict__ ml0,
                                                 float2* __restrict__ ml1) {
  int qt, h, b, half;
  if constexpr (SPLIT) {
    const int flat = ((int)blockIdx.z * 16 + (int)blockIdx.y) * 32 + (int)blockIdx.x;  // 2048
    const int swz = (flat & 7) * 256 + (flat >> 3);
    qt = 15 - (swz & 15);
    half = (swz >> 4) & 1;
    h = (swz >> 5) & 15;
    b = swz >> 9;
  } else {
    const int flat = ((int)blockIdx.z * 16 + (int)blockIdx.y) * 16 + (int)blockIdx.x;  // 1024
    const int swz = (flat & 7) * 128 + (flat >> 3);
    qt = 15 - (swz & 15);
    half = 0;
    h = (swz >> 4) & 15;
    b = swz >> 8;
  }
  const int g = h >> 1;
  const int tid = threadIdx.x;
  const int w = tid >> 6, l = tid & 63, lg = l >> 4, ll = l & 15;

  __shared__ unsigned short Klds[2][64 * 128];
  __shared__ unsigned short Vt[2][128 * 64];
  __shared__ unsigned short Ps[4][32 * 64];

  const int qr0 = qt * 128 + w * 32;
  const int kt0   = SPLIT ? (half ? qt + 1 : 0)          : 0;
  const int ktend = SPLIT ? (half ? 2 * qt + 1 : qt)     : 2 * qt + 1;
  const int kmy = 2 * qt + (w >> 1);

  s16x8 qf[2][4];
#pragma unroll
  for (int mi = 0; mi < 2; ++mi)
#pragma unroll
    for (int ks = 0; ks < 4; ++ks)
      qf[mi][ks] = *(const s16x8*)&q[(((size_t)b * S_ + qr0 + mi * 16 + ll) * NH_ + h) * D_ + ks * 32 + lg * 8];

  f32x4 o[2][8];
#pragma unroll
  for (int mi = 0; mi < 2; ++mi)
#pragma unroll
    for (int nd = 0; nd < 8; ++nd) o[mi][nd] = (f32x4){0.f, 0.f, 0.f, 0.f};
  float m_[2][4], l_[2][4];
#pragma unroll
  for (int mi = 0; mi < 2; ++mi)
#pragma unroll
    for (int j = 0; j < 4; ++j) { m_[mi][j] = NEGBIG; l_[mi][j] = 0.f; }

  const unsigned short* kbase = &kr[(((size_t)b * NH_ + h) * S_) * D_];
  const unsigned short* vbase = &vh[(((size_t)b * NKV_ + g) * S_) * D_];
  const int vk = (tid & 31) * 2, d0v = (tid >> 5) * 16;

  ushort8 va0, va1, vb0, vb1;
  {
    const unsigned short* kb0 = kbase + (size_t)kt0 * 64 * D_;
#pragma unroll
    for (int c = 0; c < 4; ++c) {
      const int ro = c * 16 + w * 4 + lg;
      const int ss = ll ^ (ro & 7);
      const unsigned short* src = kb0 + ro * D_ + ss * 8;
      char* dst = ((char*)&Klds[0][0]) + c * 4096 + w * 1024;
      __builtin_amdgcn_global_load_lds((const AS1 void*)src, (AS3 void*)dst, 16, 0, 0);
    }
    const unsigned short* v0 = vbase + (size_t)(kt0 * 64 + vk) * D_ + d0v;
    va0 = *(const ushort8*)v0; va1 = *(const ushort8*)(v0 + 8);
    vb0 = *(const ushort8*)(v0 + D_); vb1 = *(const ushort8*)(v0 + D_ + 8);
#pragma unroll
    for (int j = 0; j < 8; ++j) {
      const int d1 = d0v + j, d2 = d0v + 8 + j;
      *(unsigned int*)&Vt[0][d1 * 64 + (((vk >> 3) ^ (d1 & 7)) * 8) + (vk & 7)] =
          (unsigned int)va0[j] | ((unsigned int)vb0[j] << 16);
      *(unsigned int*)&Vt[0][d2 * 64 + (((vk >> 3) ^ (d2 & 7)) * 8) + (vk & 7)] =
          (unsigned int)va1[j] | ((unsigned int)vb1[j] << 16);
    }
  }
  __syncthreads();

  for (int kt = kt0; kt <= ktend; ++kt) {
    const int p = (kt - kt0) & 1;
    if (kt < ktend) {
      const unsigned short* kb2 = kbase + (size_t)(kt + 1) * 64 * D_;
#pragma unroll
      for (int c = 0; c < 4; ++c) {
        const int ro = c * 16 + w * 4 + lg;
        const int ss = ll ^ (ro & 7);
        const unsigned short* src = kb2 + ro * D_ + ss * 8;
        char* dst = ((char*)&Klds[p ^ 1][0]) + c * 4096 + w * 1024;
        __builtin_amdgcn_global_load_lds((const AS1 void*)src, (AS3 void*)dst, 16, 0, 0);
      }
      const unsigned short* v0 = vbase + (size_t)((kt + 1) * 64 + vk) * D_ + d0v;
      va0 = *(const ushort8*)v0; va1 = *(const ushort8*)(v0 + 8);
      vb0 = *(const ushort8*)(v0 + D_); vb1 = *(const ushort8*)(v0 + D_ + 8);
    }

    if (kt <= kmy) {
      f32x4 s[2][4];
#pragma unroll
      for (int mi = 0; mi < 2; ++mi)
#pragma unroll
        for (int ni = 0; ni < 4; ++ni) s[mi][ni] = (f32x4){0.f, 0.f, 0.f, 0.f};
#pragma unroll
      for (int ks = 0; ks < 4; ++ks) {
#pragma unroll
        for (int ni = 0; ni < 4; ++ni) {
          const int row = ni * 16 + ll;
          const s16x8 kf = *(const s16x8*)&Klds[p][row * 128 + (((ks * 4 + lg) ^ (row & 7)) * 8)];
          s[0][ni] = __builtin_amdgcn_mfma_f32_16x16x32_bf16(qf[0][ks], kf, s[0][ni], 0, 0, 0);
          s[1][ni] = __builtin_amdgcn_mfma_f32_16x16x32_bf16(qf[1][ks], kf, s[1][ni], 0, 0, 0);
        }
      }

      const bool diag = (kt == kmy);
      float lm[2][4];
#pragma unroll
      for (int mi = 0; mi < 2; ++mi)
#pragma unroll
        for (int j = 0; j < 4; ++j) {
          if (diag) {
            const int qg = qr0 + mi * 16 + lg * 4 + j;
#pragma unroll
            for (int ni = 0; ni < 4; ++ni)
              if (kt * 64 + ni * 16 + ll > qg) s[mi][ni][j] = NEGBIG;
          }
          lm[mi][j] = fmaxf(fmaxf(s[mi][0][j], s[mi][1][j]),
                            fmaxf(s[mi][2][j], s[mi][3][j]));
        }
      float excess = lm[0][0] - m_[0][0];
#pragma unroll
      for (int mi = 0; mi < 2; ++mi)
#pragma unroll
        for (int j = 0; j < 4; ++j) excess = fmaxf(excess, lm[mi][j] - m_[mi][j]);
      const bool slow = __any(excess > 11.5f);

#pragma unroll
      for (int mi = 0; mi < 2; ++mi)
#pragma unroll
        for (int j = 0; j < 4; ++j) {
          float ps_[4];
          if (slow) {
            float mt = lm[mi][j];
            mt = fmaxf(mt, __shfl_xor(mt, 1));
            mt = fmaxf(mt, __shfl_xor(mt, 2));
            mt = fmaxf(mt, __shfl_xor(mt, 4));
            mt = fmaxf(mt, __shfl_xor(mt, 8));
            const float mnew = fmaxf(m_[mi][j], mt);
            const float al = exp2f(m_[mi][j] - mnew);
            m_[mi][j] = mnew;
            float sum = 0.f;
#pragma unroll
            for (int ni = 0; ni < 4; ++ni) { ps_[ni] = exp2f(s[mi][ni][j] - mnew); sum += ps_[ni]; }
            l_[mi][j] = l_[mi][j] * al + sum;
#pragma unroll
            for (int nd = 0; nd < 8; ++nd) o[mi][nd][j] *= al;
          } else {
            float sum = 0.f;
#pragma unroll
            for (int ni = 0; ni < 4; ++ni) { ps_[ni] = exp2f(s[mi][ni][j] - m_[mi][j]); sum += ps_[ni]; }
            l_[mi][j] += sum;
          }
          const int prow = mi * 16 + lg * 4 + j;
#pragma unroll
          for (int nq = 0; nq < 2; ++nq) {
            unsigned int u;
            asm("v_cvt_pk_bf16_f32 %0, %1, %2" : "=v"(u) : "v"(ps_[nq * 2]), "v"(ps_[nq * 2 + 1]));
            const int c0 = nq * 32 + ll, c1 = nq * 32 + 16 + ll;
            Ps[w][prow * 64 + (((c0 >> 3) ^ (prow & 7)) * 8) + (ll & 7)] = (unsigned short)u;
            Ps[w][prow * 64 + (((c1 >> 3) ^ (prow & 7)) * 8) + (ll & 7)] = (unsigned short)(u >> 16);
          }
        }

      s16x8 pa[2][2];
#pragma unroll
      for (int mi = 0; mi < 2; ++mi)
#pragma unroll
        for (int ks2 = 0; ks2 < 2; ++ks2) {
          const int prow = mi * 16 + ll;
          pa[mi][ks2] = *(const s16x8*)&Ps[w][prow * 64 + (((ks2 * 4 + lg) ^ (prow & 7)) * 8)];
        }
#pragma unroll
      for (int nd = 0; nd < 8; ++nd) {
#pragma unroll
        for (int ks2 = 0; ks2 < 2; ++ks2) {
          const int vr = nd * 16 + ll;
          const s16x8 vbf = *(const s16x8*)&Vt[p][vr * 64 + (((ks2 * 4 + lg) ^ (vr & 7)) * 8)];
          o[0][nd] = __builtin_amdgcn_mfma_f32_16x16x32_bf16(pa[0][ks2], vbf, o[0][nd], 0, 0, 0);
          o[1][nd] = __builtin_amdgcn_mfma_f32_16x16x32_bf16(pa[1][ks2], vbf, o[1][nd], 0, 0, 0);
        }
      }
    }

    if (kt < ktend) {
#pragma unroll
      for (int j = 0; j < 8; ++j) {
        const int d1 = d0v + j, d2 = d0v + 8 + j;
        *(unsigned int*)&Vt[p ^ 1][d1 * 64 + (((vk >> 3) ^ (d1 & 7)) * 8) + (vk & 7)] =
            (unsigned int)va0[j] | ((unsigned int)vb0[j] << 16);
        *(unsigned int*)&Vt[p ^ 1][d2 * 64 + (((vk >> 3) ^ (d2 & 7)) * 8) + (vk & 7)] =
            (unsigned int)va1[j] | ((unsigned int)vb1[j] << 16);
      }
    }
    __syncthreads();
  }

  // ---- epilogue
#pragma unroll
  for (int mi = 0; mi < 2; ++mi)
#pragma unroll
    for (int j = 0; j < 4; ++j) {
      float ls = l_[mi][j];
      ls += __shfl_xor(ls, 1);
      ls += __shfl_xor(ls, 2);
      ls += __shfl_xor(ls, 4);
      ls += __shfl_xor(ls, 8);
      if constexpr (SPLIT) {
        unsigned short* Ph = half ? P1 : P0;
        float2* mlh = half ? ml1 : ml0;
        const size_t ridx = ((size_t)b * NH_ + h) * S_ + qr0 + mi * 16 + lg * 4 + j;
        unsigned short* op = &Ph[ridx * D_ + ll];
#pragma unroll
        for (int nd = 0; nd < 8; ++nd) op[nd * 16] = f2bf(o[mi][nd][j]);
        if (ll == 0) mlh[ridx] = make_float2(m_[mi][j], ls);
      } else {
        const float inv = 1.f / ls;
        const size_t rowg = (size_t)b * S_ + qr0 + mi * 16 + lg * 4 + j;
        unsigned short* op = &outp[rowg * (NH_ * D_) + h * D_ + ll];
#pragma unroll
        for (int nd = 0; nd < 8; ++nd) op[nd * 16] = f2bf(o[mi][nd][j] * inv);
      }
    }
}

// ---------------------------------------------------------------------------
// Combine split-KV partials: out = (a0*O~0 + a1*O~1) / (a0*l0 + a1*l1),
// ai = 2^(mi - max(m0,m1)). Block per (s,b), thread owns (h, 8 d's).
// ---------------------------------------------------------------------------
__global__ __launch_bounds__(256) void attn_combine(const unsigned short* __restrict__ P0,
                                                    const unsigned short* __restrict__ P1,
                                                    const float2* __restrict__ ml0,
                                                    const float2* __restrict__ ml1,
                                                    unsigned short* __restrict__ outp) {
  const int s = blockIdx.x, b = blockIdx.y;
  const int tid = threadIdx.x;
  const int h = tid >> 4, d0 = (tid & 15) * 8;
  const size_t ridx = ((size_t)b * NH_ + h) * S_ + s;
  const float2 a = ml0[ridx], c = ml1[ridx];
  const float m = fmaxf(a.x, c.x);
  const float a0 = exp2f(a.x - m), a1 = exp2f(c.x - m);
  const float inv = 1.f / (a0 * a.y + a1 * c.y);
  const ushort8 u0 = *(const ushort8*)&P0[ridx * D_ + d0];
  const ushort8 u1 = *(const ushort8*)&P1[ridx * D_ + d0];
  ushort8 r;
#pragma unroll
  for (int j = 0; j < 8; ++j)
    r[j] = f2bf((a0 * bf2f(u0[j]) + a1 * bf2f(u1[j])) * inv);
  *(ushort8*)&outp[((size_t)b * S_ + s) * (NH_ * D_) + h * D_ + d0] = r;
}

// ---------------------------------------------------------------------------
// Host launch
// ---------------------------------------------------------------------------
extern "C" void kernel_launch(void* const* d_in, const int* in_sizes, int n_in,
                              void* d_out, int out_size, void* d_ws, size_t ws_size,
                              hipStream_t stream) {
  const float* hidden = (const float*)d_in[0];
  const float* cosT   = (const float*)d_in[1];
  const float* sinT   = (const float*)d_in[2];
  const float* W_q    = (const float*)d_in[5];
  const float* W_k    = (const float*)d_in[6];
  const float* W_v    = (const float*)d_in[7];
  const float* W_o    = (const float*)d_in[8];
  const float* Vr     = (const float*)d_in[9];
  const float* Zv     = (const float*)d_in[10];
  float* out = (float*)d_out;

  // base workspace map (bytes) -- verified fits at 130,023,424
  char* ws = (char*)d_ws;
  unsigned short* hb     = (unsigned short*)(ws + 0);           // 32MB hidden bf16
  unsigned short* attn_b = (unsigned short*)(ws + 0);           // fallback attn out
  unsigned short* P0     = (unsigned short*)(ws + 0);           // split: half-A O~ (B,NH,S,D)
  unsigned short* q_b    = (unsigned short*)(ws + 33554432);    // 32MB (B,S,NH,D); split: combine out
  unsigned short* kr_b   = (unsigned short*)(ws + 67108864);    // 32MB (B,NH,S,D)
  unsigned short* Wf     = (unsigned short*)(ws + 100663296);   // 1.5MB fused weights -> vh later
  unsigned short* vh_b   = (unsigned short*)(ws + 100663296);   // 16MB (B,NKV,S,D)
  unsigned short* WR1    = (unsigned short*)(ws + 117440512);   // 8MB Wq bf16 -> Wo bf16
  float*          pkpv   = (float*)(ws + 117440512);            // 12.6MB [M][384] f32
  // split-only extension
  unsigned short* P1     = (unsigned short*)(ws + 130023424);   // 32MB half-B O~
  float2*         ml0    = (float2*)(ws + 163577856);           // 1MB
  float2*         ml1    = (float2*)(ws + 164626432);           // 1MB
  const size_t NEED_SPLIT = 165675008ull;
  const bool split = (ws_size >= NEED_SPLIT);

  const int M = B_ * S_;

  // 1) conversions + Q projection
  cvt_bf16<<<2048, 256, 0, stream>>>(hidden, hb, (B_ * S_ * HID_) / 8);
  cvt_bf16<<<2048, 256, 0, stream>>>(W_q, WR1, (HID_ * HID_) / 8);
  gemm_mfma<true><<<dim3(16, 64), 256, 0, stream>>>(hb, WR1, q_b, M, 2048, HID_);

  // 2) fused low-rank weights + direct pk|pv GEMM
  wfuse<<<dim3(24, 8), 256, 0, stream>>>(W_k, W_v, Vr, Zv, Wf);
  gemm_mfma<false><<<dim3(3, 64), 256, 0, stream>>>(hb, Wf, pkpv, M, 384, HID_);

  // 3) rope(q) in place
  rope_q<<<(B_ * S_ * NH_ * 64) / 256, 256, 0, stream>>>(q_b, cosT, sinT);

  // 4) expand K (+rope) and V
  expand_k<<<dim3(S_ / 32, NH_, B_), 256, 0, stream>>>(pkpv, Vr, cosT, sinT, kr_b);
  expand_v<<<dim3(S_ / 32, NKV_, B_), 256, 0, stream>>>(pkpv, Zv, vh_b);

  // 5) Wo conversion (pkpv dead after expanders)
  cvt_bf16<<<2048, 256, 0, stream>>>(W_o, WR1, (HID_ * HID_) / 8);

  // 6) attention
  if (split) {
    attn_mfma<true><<<dim3(32, 16, 4), 256, 0, stream>>>(q_b, kr_b, vh_b, nullptr,
                                                         P0, P1, ml0, ml1);
    attn_combine<<<dim3(S_, B_), 256, 0, stream>>>(P0, P1, ml0, ml1, q_b);  // q dead -> reuse
    gemm_mfma<false><<<dim3(16, 64), 256, 0, stream>>>(q_b, WR1, out, M, HID_, HID_);
  } else {
    attn_mfma<false><<<dim3(16, 16, 4), 256, 0, stream>>>(q_b, kr_b, vh_b, attn_b,
                                                          nullptr, nullptr, nullptr, nullptr);
    gemm_mfma<false><<<dim3(16, 64), 256, 0, stream>>>(attn_b, WR1, out, M, HID_, HID_);
  }
}

// Round 12
// 707.976 us; speedup vs baseline: 1.3381x; 1.0551x over previous
//
#include <hip/hip_runtime.h>

typedef unsigned short ushort8 __attribute__((ext_vector_type(8)));
typedef short s16x8 __attribute__((ext_vector_type(8)));
typedef float f32x4 __attribute__((ext_vector_type(4)));

#define AS1 __attribute__((address_space(1)))
#define AS3 __attribute__((address_space(3)))

#define B_    4
#define S_    2048
#define HID_  2048
#define NH_   16
#define NKV_  8
#define D_    128
#define RK_   16
#define SCALING_ 0.08838834764831845f   // 128^-0.5
#define LOG2E_   1.4426950408889634f
#define NEGBIG   -1.0e30f

__device__ __forceinline__ float bf2f(unsigned short u) {
  union { unsigned int i; float f; } x; x.i = ((unsigned int)u) << 16; return x.f;
}
__device__ __forceinline__ unsigned short f2bf(float f) {
  union { float f; unsigned int i; } x; x.f = f;
  unsigned int r = x.i + 0x7fffu + ((x.i >> 16) & 1u);
  return (unsigned short)(r >> 16);
}

// ---------------------------------------------------------------------------
// f32 -> bf16 conversion, 8 elems/thread, grid-stride.
// ---------------------------------------------------------------------------
__global__ __launch_bounds__(256) void cvt_bf16(const float* __restrict__ in,
                                                unsigned short* __restrict__ out,
                                                int n8) {
  int i = blockIdx.x * 256 + threadIdx.x;
  const int stride = gridDim.x * 256;
  for (; i < n8; i += stride) {
    const float4 a = ((const float4*)in)[i * 2];
    const float4 b = ((const float4*)in)[i * 2 + 1];
    ushort8 u;
    u[0] = f2bf(a.x); u[1] = f2bf(a.y); u[2] = f2bf(a.z); u[3] = f2bf(a.w);
    u[4] = f2bf(b.x); u[5] = f2bf(b.y); u[6] = f2bf(b.z); u[7] = f2bf(b.w);
    *(ushort8*)&out[i * 8] = u;
  }
}

// ---------------------------------------------------------------------------
// Fused low-rank weights, bf16 out [384][2048].
// ---------------------------------------------------------------------------
__global__ __launch_bounds__(256) void wfuse(const float* __restrict__ W_k,
                                             const float* __restrict__ W_v,
                                             const float* __restrict__ Vr,
                                             const float* __restrict__ Zv,
                                             unsigned short* __restrict__ Wf) {
  const int idx = blockIdx.x;
  const int cc = blockIdx.y * 256;
  const int tid = threadIdx.x;
  const bool isK = idx < 16;
  const int hg = isK ? idx : (idx - 16);
  const int wrow0 = isK ? (idx * 16) : (256 + (idx - 16) * 16);
  const float* W = isK ? &W_k[(size_t)((hg >> 1) * 128) * HID_]
                       : &W_v[(size_t)(hg * 128) * HID_];
  const float* P = isK ? &Vr[(size_t)hg * 128 * 16] : &Zv[(size_t)hg * 128 * 16];
  __shared__ float Wl[32][257];
  float acc[16] = {};
  for (int d0 = 0; d0 < 128; d0 += 32) {
    __syncthreads();
#pragma unroll 8
    for (int dd = 0; dd < 32; ++dd)
      Wl[dd][tid] = W[(size_t)(d0 + dd) * HID_ + cc + tid];
    __syncthreads();
#pragma unroll 8
    for (int dd = 0; dd < 32; ++dd) {
      const float w = Wl[dd][tid];
#pragma unroll
      for (int r = 0; r < 16; ++r) acc[r] += w * P[(d0 + dd) * 16 + r];
    }
  }
#pragma unroll
  for (int r = 0; r < 16; ++r)
    Wf[(size_t)(wrow0 + r) * HID_ + cc + tid] = f2bf(acc[r]);
}

// ---------------------------------------------------------------------------
// m97-style MFMA GEMM (kept for the small N=384 pkpv GEMM).
// ---------------------------------------------------------------------------
template<bool CBF>
__global__ __launch_bounds__(256) void gemm_mfma(const unsigned short* __restrict__ A,
                                                 const unsigned short* __restrict__ Bb,
                                                 void* __restrict__ C_,
                                                 int M, int N, int K) {
  __shared__ unsigned short Ash[128 * 64];
  __shared__ unsigned short Bsh[128 * 64];
  const int tid = threadIdx.x;
  const int w = tid >> 6, l = tid & 63, lg = l >> 4, ll = l & 15;
  const int wr = w >> 1, wc = w & 1;
  const int flat = blockIdx.y * gridDim.x + blockIdx.x;
  const int cpx = (gridDim.x * gridDim.y) >> 3;
  const int swz = (flat & 7) * cpx + (flat >> 3);
  const int bm = (swz / gridDim.x) * 128, bn = (swz % gridDim.x) * 128;

  f32x4 acc[4][4];
#pragma unroll
  for (int i = 0; i < 4; i++)
#pragma unroll
    for (int j = 0; j < 4; j++) acc[i][j] = (f32x4){0.f, 0.f, 0.f, 0.f};

  const int srow = tid >> 3;
  const int sslot = tid & 7;

  for (int k0 = 0; k0 < K; k0 += 64) {
    __syncthreads();
#pragma unroll
    for (int c = 0; c < 4; ++c) {
      const int row = c * 32 + srow;
      const int ss = sslot ^ (row & 7);
      const unsigned short* srcA = &A[(size_t)(bm + row) * K + k0 + ss * 8];
      const unsigned short* srcB = &Bb[(size_t)(bn + row) * K + k0 + ss * 8];
      char* dstA = ((char*)Ash) + c * 4096 + w * 1024;
      char* dstB = ((char*)Bsh) + c * 4096 + w * 1024;
      __builtin_amdgcn_global_load_lds((const AS1 void*)srcA, (AS3 void*)dstA, 16, 0, 0);
      __builtin_amdgcn_global_load_lds((const AS1 void*)srcB, (AS3 void*)dstB, 16, 0, 0);
    }
    __syncthreads();

#pragma unroll
    for (int ks = 0; ks < 2; ++ks) {
      s16x8 af[4], bf_[4];
#pragma unroll
      for (int mi = 0; mi < 4; ++mi) {
        const int row = wr * 64 + mi * 16 + ll;
        af[mi] = *(const s16x8*)&Ash[row * 64 + (((ks * 4 + lg) ^ (row & 7)) * 8)];
      }
#pragma unroll
      for (int ni = 0; ni < 4; ++ni) {
        const int row = wc * 64 + ni * 16 + ll;
        bf_[ni] = *(const s16x8*)&Bsh[row * 64 + (((ks * 4 + lg) ^ (row & 7)) * 8)];
      }
#pragma unroll
      for (int mi = 0; mi < 4; ++mi)
#pragma unroll
        for (int ni = 0; ni < 4; ++ni)
          acc[mi][ni] = __builtin_amdgcn_mfma_f32_16x16x32_bf16(af[mi], bf_[ni], acc[mi][ni], 0, 0, 0);
    }
  }

#pragma unroll
  for (int mi = 0; mi < 4; ++mi)
#pragma unroll
    for (int ni = 0; ni < 4; ++ni)
#pragma unroll
      for (int j = 0; j < 4; ++j) {
        const int row = bm + wr * 64 + mi * 16 + lg * 4 + j;
        const int col = bn + wc * 64 + ni * 16 + ll;
        if (CBF) ((unsigned short*)C_)[(size_t)row * N + col] = f2bf(acc[mi][ni][j]);
        else     ((float*)C_)[(size_t)row * N + col] = acc[mi][ni][j];
      }
}

// ---------------------------------------------------------------------------
// 8-phase 256x256 MFMA GEMM (T3+T4+T5). 512 thr = 8 waves (2M x 4N), BK=64.
// LDS = 2 slots x (A 256x64 + B 256x64) bf16 = 128KB; grid = 1 block/CU.
// Per K-tile: 4 phases = gray-coded C-quadrants (mih,nih); each phase:
//   [vmcnt(N); raw s_barrier] -> 12x ds_read_b128 -> 16 MFMA (setprio) ->
//   issue prefetch half-tiles of tile t+1 into the other slot.
// Prefetch issue order A0,B0 | B1 | A1 across phases 0-2 => per-wave FIFO
// waits: vmcnt(4), vmcnt(6), vmcnt(6), none. Raw barriers (no __syncthreads
// drain). Slot t+1 writes are safe anywhere in tile t (last read ended t-1).
// ---------------------------------------------------------------------------
template<bool CBF>
__global__ __launch_bounds__(512) void gemm256_8ph(const unsigned short* __restrict__ A,
                                                   const unsigned short* __restrict__ Bb,
                                                   void* __restrict__ C_,
                                                   int M, int N, int K) {
  __shared__ unsigned short Lds[2][2][256 * 64];   // [slot][0=A,1=B][row*64+col]
  const int tid = threadIdx.x;
  const int w = tid >> 6, l = tid & 63, lg = l >> 4, ll = l & 15;
  const int wr = w >> 2;        // 0..1  (M)
  const int wc = w & 3;         // 0..3  (N)
  const int flat = blockIdx.y * gridDim.x + blockIdx.x;
  const int cpx = (gridDim.x * gridDim.y) >> 3;
  const int swz = (flat & 7) * cpx + (flat >> 3);
  const int bm = (swz / gridDim.x) * 256, bn = (swz % gridDim.x) * 256;

  f32x4 acc[8][4];
#pragma unroll
  for (int i = 0; i < 8; i++)
#pragma unroll
    for (int j = 0; j < 4; j++) acc[i][j] = (f32x4){0.f, 0.f, 0.f, 0.f};

  // stage one 128-row half-tile (16KB) of operand op for K-offset kk into slot
  auto stage = [&](int op, int hh, int slot, int kk) {
    const unsigned short* base = (op == 0) ? A : Bb;
    const int r0 = (op == 0) ? bm : bn;
#pragma unroll
    for (int i = 0; i < 2; ++i) {
      const int r = hh * 128 + i * 64 + (tid >> 3);
      const int ss = (tid & 7) ^ (r & 7);
      const unsigned short* src = &base[(size_t)(r0 + r) * K + kk + ss * 8];
      unsigned short* dstb = &Lds[slot][op][(hh * 128 + i * 64 + (w << 3)) * 64];
      __builtin_amdgcn_global_load_lds((const AS1 void*)src, (AS3 void*)dstb, 16, 0, 0);
    }
  };

  const int NT = K >> 6;

  // prologue: stage tile 0 into slot 0 in FIFO order A0,B0,B1,A1
  stage(0, 0, 0, 0);
  stage(1, 0, 0, 0);
  stage(1, 1, 0, 0);
  stage(0, 1, 0, 0);

#define GPHASE(MIH, NIH, WAITN, DO_PF)                                          \
  {                                                                             \
    if (WAITN == 4)      asm volatile("s_waitcnt vmcnt(4)" ::: "memory");       \
    else if (WAITN == 6) asm volatile("s_waitcnt vmcnt(6)" ::: "memory");       \
    __builtin_amdgcn_sched_barrier(0);                                          \
    __builtin_amdgcn_s_barrier();                                               \
    __builtin_amdgcn_sched_barrier(0);                                          \
    s16x8 af[4][2], bf_[2][2];                                                  \
    _Pragma("unroll")                                                           \
    for (int mi2 = 0; mi2 < 4; ++mi2)                                           \
      _Pragma("unroll")                                                         \
      for (int ks = 0; ks < 2; ++ks) {                                          \
        const int row = (MIH) * 128 + wr * 64 + mi2 * 16 + ll;                  \
        af[mi2][ks] = *(const s16x8*)&Lds[s][0][row * 64 +                      \
                          (((ks * 4 + lg) ^ (row & 7)) * 8)];                   \
      }                                                                         \
    _Pragma("unroll")                                                           \
    for (int ni2 = 0; ni2 < 2; ++ni2)                                           \
      _Pragma("unroll")                                                         \
      for (int ks = 0; ks < 2; ++ks) {                                          \
        const int row = (NIH) * 128 + wc * 32 + ni2 * 16 + ll;                  \
        bf_[ni2][ks] = *(const s16x8*)&Lds[s][1][row * 64 +                     \
                          (((ks * 4 + lg) ^ (row & 7)) * 8)];                   \
      }                                                                         \
    __builtin_amdgcn_s_setprio(1);                                              \
    _Pragma("unroll")                                                           \
    for (int mi2 = 0; mi2 < 4; ++mi2)                                           \
      _Pragma("unroll")                                                         \
      for (int ni2 = 0; ni2 < 2; ++ni2)                                         \
        _Pragma("unroll")                                                       \
        for (int ks = 0; ks < 2; ++ks)                                          \
          acc[(MIH) * 4 + mi2][(NIH) * 2 + ni2] =                               \
              __builtin_amdgcn_mfma_f32_16x16x32_bf16(                          \
                  af[mi2][ks], bf_[ni2][ks],                                    \
                  acc[(MIH) * 4 + mi2][(NIH) * 2 + ni2], 0, 0, 0);              \
    __builtin_amdgcn_s_setprio(0);                                              \
    DO_PF                                                                       \
  }

  for (int t = 0; t < NT; ++t) {
    const int s = t & 1;
    const int s2 = s ^ 1;
    const bool hn = (t + 1 < NT);
    const int k1 = (t + 1) << 6;
    GPHASE(0, 0, 4, { if (hn) { stage(0, 0, s2, k1); stage(1, 0, s2, k1); } })
    GPHASE(0, 1, 6, { if (hn) { stage(1, 1, s2, k1); } })
    GPHASE(1, 1, 6, { if (hn) { stage(0, 1, s2, k1); } })
    GPHASE(1, 0, 0, {})
  }
#undef GPHASE

  // epilogue: write C
#pragma unroll
  for (int mih = 0; mih < 2; ++mih)
#pragma unroll
    for (int mi2 = 0; mi2 < 4; ++mi2)
#pragma unroll
      for (int nih = 0; nih < 2; ++nih)
#pragma unroll
        for (int ni2 = 0; ni2 < 2; ++ni2)
#pragma unroll
          for (int j = 0; j < 4; ++j) {
            const int row = bm + mih * 128 + wr * 64 + mi2 * 16 + lg * 4 + j;
            const int col = bn + nih * 128 + wc * 32 + ni2 * 16 + ll;
            const float v = acc[mih * 4 + mi2][nih * 2 + ni2][j];
            if (CBF) ((unsigned short*)C_)[(size_t)row * N + col] = f2bf(v);
            else     ((float*)C_)[(size_t)row * N + col] = v;
          }
}

// ---------------------------------------------------------------------------
// In-place RoPE on bf16 q, folding SCALING*log2(e).
// ---------------------------------------------------------------------------
__global__ __launch_bounds__(256) void rope_q(unsigned short* __restrict__ q,
                                              const float* __restrict__ cosT,
                                              const float* __restrict__ sinT) {
  const int p = blockIdx.x * 256 + threadIdx.x;
  const int d = p & 63;
  const int h = (p >> 6) & 15;
  const int s = (p >> 10) & 2047;
  const int b = p >> 21;
  const size_t base = (((size_t)b * S_ + s) * NH_ + h) * D_ + d;
  const float x1 = bf2f(q[base]), x2 = bf2f(q[base + 64]);
  const float c = cosT[s * 64 + d], sn = sinT[s * 64 + d];
  const float sc = SCALING_ * LOG2E_;
  q[base]      = f2bf((x1 * c - x2 * sn) * sc);
  q[base + 64] = f2bf((x1 * sn + x2 * c) * sc);
}

// ---------------------------------------------------------------------------
// Expand pk (fused [M][384] f32, cols h*16+r) -> k_rot bf16 (B,NH,S,D) +RoPE.
// ---------------------------------------------------------------------------
__global__ __launch_bounds__(256) void expand_k(const float* __restrict__ pkpv,
                                                const float* __restrict__ Vr,
                                                const float* __restrict__ cosT,
                                                const float* __restrict__ sinT,
                                                unsigned short* __restrict__ kr) {
  const int s0 = blockIdx.x * 32, h = blockIdx.y, b = blockIdx.z;
  const int tid = threadIdx.x;
  __shared__ float pkS[32][17];
  if (tid < 128) {
    const int r_ = tid >> 2, c4 = (tid & 3) * 4;
    float4 v = *(const float4*)&pkpv[(size_t)(b * S_ + s0 + r_) * 384 + h * 16 + c4];
    pkS[r_][c4 + 0] = v.x; pkS[r_][c4 + 1] = v.y;
    pkS[r_][c4 + 2] = v.z; pkS[r_][c4 + 3] = v.w;
  }
  __syncthreads();
  const int row = tid >> 3, dl = tid & 7;
  float kh[16];
#pragma unroll
  for (int j = 0; j < 16; j++) {
    const int d = dl + 8 * j;
    const float4* w = (const float4*)&Vr[((size_t)h * D_ + d) * RK_];
    float a = 0.f;
#pragma unroll
    for (int q4 = 0; q4 < 4; q4++) {
      float4 wv = w[q4];
      a += pkS[row][q4 * 4 + 0] * wv.x + pkS[row][q4 * 4 + 1] * wv.y
         + pkS[row][q4 * 4 + 2] * wv.z + pkS[row][q4 * 4 + 3] * wv.w;
    }
    kh[j] = a;
  }
  const int pos = s0 + row;
  const size_t o = (((size_t)b * NH_ + h) * S_ + pos) * D_;
#pragma unroll
  for (int j = 0; j < 8; j++) {
    const int d = dl + 8 * j;
    const float c = cosT[pos * 64 + d], sn = sinT[pos * 64 + d];
    kr[o + d]      = f2bf(kh[j] * c - kh[j + 8] * sn);
    kr[o + d + 64] = f2bf(kh[j] * sn + kh[j + 8] * c);
  }
}

// ---------------------------------------------------------------------------
// Expand pv (cols 256+g*16+r) -> v_hat bf16 (B,NKV,S,D).
// ---------------------------------------------------------------------------
__global__ __launch_bounds__(256) void expand_v(const float* __restrict__ pkpv,
                                                const float* __restrict__ Zv,
                                                unsigned short* __restrict__ vh) {
  const int s0 = blockIdx.x * 32, g = blockIdx.y, b = blockIdx.z;
  const int tid = threadIdx.x;
  __shared__ float pvS[32][17];
  if (tid < 128) {
    const int r_ = tid >> 2, c4 = (tid & 3) * 4;
    float4 v = *(const float4*)&pkpv[(size_t)(b * S_ + s0 + r_) * 384 + 256 + g * 16 + c4];
    pvS[r_][c4 + 0] = v.x; pvS[r_][c4 + 1] = v.y;
    pvS[r_][c4 + 2] = v.z; pvS[r_][c4 + 3] = v.w;
  }
  __syncthreads();
  const int row = tid >> 3, dl = tid & 7;
  const size_t o = (((size_t)b * NKV_ + g) * S_ + s0 + row) * D_;
#pragma unroll
  for (int j = 0; j < 16; j++) {
    const int d = dl + 8 * j;
    const float4* w = (const float4*)&Zv[((size_t)g * D_ + d) * RK_];
    float a = 0.f;
#pragma unroll
    for (int q4 = 0; q4 < 4; q4++) {
      float4 wv = w[q4];
      a += pvS[row][q4 * 4 + 0] * wv.x + pvS[row][q4 * 4 + 1] * wv.y
         + pvS[row][q4 * 4 + 2] * wv.z + pvS[row][q4 * 4 + 3] * wv.w;
    }
    vh[o + d] = f2bf(a);
  }
}

// ---------------------------------------------------------------------------
// MFMA flash attention (round-11 split version, unchanged).
// ---------------------------------------------------------------------------
template<bool SPLIT>
__global__ __launch_bounds__(256) void attn_mfma(const unsigned short* __restrict__ q,
                                                 const unsigned short* __restrict__ kr,
                                                 const unsigned short* __restrict__ vh,
                                                 unsigned short* __restrict__ outp,
                                                 unsigned short* __restrict__ P0,
                                                 unsigned short* __restrict__ P1,
                                                 float2* __restrict__ ml0,
                                                 float2* __restrict__ ml1) {
  int qt, h, b, half;
  if constexpr (SPLIT) {
    const int flat = ((int)blockIdx.z * 16 + (int)blockIdx.y) * 32 + (int)blockIdx.x;
    const int swz = (flat & 7) * 256 + (flat >> 3);
    qt = 15 - (swz & 15);
    half = (swz >> 4) & 1;
    h = (swz >> 5) & 15;
    b = swz >> 9;
  } else {
    const int flat = ((int)blockIdx.z * 16 + (int)blockIdx.y) * 16 + (int)blockIdx.x;
    const int swz = (flat & 7) * 128 + (flat >> 3);
    qt = 15 - (swz & 15);
    half = 0;
    h = (swz >> 4) & 15;
    b = swz >> 8;
  }
  const int g = h >> 1;
  const int tid = threadIdx.x;
  const int w = tid >> 6, l = tid & 63, lg = l >> 4, ll = l & 15;

  __shared__ unsigned short Klds[2][64 * 128];
  __shared__ unsigned short Vt[2][128 * 64];
  __shared__ unsigned short Ps[4][32 * 64];

  const int qr0 = qt * 128 + w * 32;
  const int kt0   = SPLIT ? (half ? qt + 1 : 0)          : 0;
  const int ktend = SPLIT ? (half ? 2 * qt + 1 : qt)     : 2 * qt + 1;
  const int kmy = 2 * qt + (w >> 1);

  s16x8 qf[2][4];
#pragma unroll
  for (int mi = 0; mi < 2; ++mi)
#pragma unroll
    for (int ks = 0; ks < 4; ++ks)
      qf[mi][ks] = *(const s16x8*)&q[(((size_t)b * S_ + qr0 + mi * 16 + ll) * NH_ + h) * D_ + ks * 32 + lg * 8];

  f32x4 o[2][8];
#pragma unroll
  for (int mi = 0; mi < 2; ++mi)
#pragma unroll
    for (int nd = 0; nd < 8; ++nd) o[mi][nd] = (f32x4){0.f, 0.f, 0.f, 0.f};
  float m_[2][4], l_[2][4];
#pragma unroll
  for (int mi = 0; mi < 2; ++mi)
#pragma unroll
    for (int j = 0; j < 4; ++j) { m_[mi][j] = NEGBIG; l_[mi][j] = 0.f; }

  const unsigned short* kbase = &kr[(((size_t)b * NH_ + h) * S_) * D_];
  const unsigned short* vbase = &vh[(((size_t)b * NKV_ + g) * S_) * D_];
  const int vk = (tid & 31) * 2, d0v = (tid >> 5) * 16;

  ushort8 va0, va1, vb0, vb1;
  {
    const unsigned short* kb0 = kbase + (size_t)kt0 * 64 * D_;
#pragma unroll
    for (int c = 0; c < 4; ++c) {
      const int ro = c * 16 + w * 4 + lg;
      const int ss = ll ^ (ro & 7);
      const unsigned short* src = kb0 + ro * D_ + ss * 8;
      char* dst = ((char*)&Klds[0][0]) + c * 4096 + w * 1024;
      __builtin_amdgcn_global_load_lds((const AS1 void*)src, (AS3 void*)dst, 16, 0, 0);
    }
    const unsigned short* v0 = vbase + (size_t)(kt0 * 64 + vk) * D_ + d0v;
    va0 = *(const ushort8*)v0; va1 = *(const ushort8*)(v0 + 8);
    vb0 = *(const ushort8*)(v0 + D_); vb1 = *(const ushort8*)(v0 + D_ + 8);
#pragma unroll
    for (int j = 0; j < 8; ++j) {
      const int d1 = d0v + j, d2 = d0v + 8 + j;
      *(unsigned int*)&Vt[0][d1 * 64 + (((vk >> 3) ^ (d1 & 7)) * 8) + (vk & 7)] =
          (unsigned int)va0[j] | ((unsigned int)vb0[j] << 16);
      *(unsigned int*)&Vt[0][d2 * 64 + (((vk >> 3) ^ (d2 & 7)) * 8) + (vk & 7)] =
          (unsigned int)va1[j] | ((unsigned int)vb1[j] << 16);
    }
  }
  __syncthreads();

  for (int kt = kt0; kt <= ktend; ++kt) {
    const int p = (kt - kt0) & 1;
    if (kt < ktend) {
      const unsigned short* kb2 = kbase + (size_t)(kt + 1) * 64 * D_;
#pragma unroll
      for (int c = 0; c < 4; ++c) {
        const int ro = c * 16 + w * 4 + lg;
        const int ss = ll ^ (ro & 7);
        const unsigned short* src = kb2 + ro * D_ + ss * 8;
        char* dst = ((char*)&Klds[p ^ 1][0]) + c * 4096 + w * 1024;
        __builtin_amdgcn_global_load_lds((const AS1 void*)src, (AS3 void*)dst, 16, 0, 0);
      }
      const unsigned short* v0 = vbase + (size_t)((kt + 1) * 64 + vk) * D_ + d0v;
      va0 = *(const ushort8*)v0; va1 = *(const ushort8*)(v0 + 8);
      vb0 = *(const ushort8*)(v0 + D_); vb1 = *(const ushort8*)(v0 + D_ + 8);
    }

    if (kt <= kmy) {
      f32x4 s[2][4];
#pragma unroll
      for (int mi = 0; mi < 2; ++mi)
#pragma unroll
        for (int ni = 0; ni < 4; ++ni) s[mi][ni] = (f32x4){0.f, 0.f, 0.f, 0.f};
#pragma unroll
      for (int ks = 0; ks < 4; ++ks) {
#pragma unroll
        for (int ni = 0; ni < 4; ++ni) {
          const int row = ni * 16 + ll;
          const s16x8 kf = *(const s16x8*)&Klds[p][row * 128 + (((ks * 4 + lg) ^ (row & 7)) * 8)];
          s[0][ni] = __builtin_amdgcn_mfma_f32_16x16x32_bf16(qf[0][ks], kf, s[0][ni], 0, 0, 0);
          s[1][ni] = __builtin_amdgcn_mfma_f32_16x16x32_bf16(qf[1][ks], kf, s[1][ni], 0, 0, 0);
        }
      }

      const bool diag = (kt == kmy);
      float lm[2][4];
#pragma unroll
      for (int mi = 0; mi < 2; ++mi)
#pragma unroll
        for (int j = 0; j < 4; ++j) {
          if (diag) {
            const int qg = qr0 + mi * 16 + lg * 4 + j;
#pragma unroll
            for (int ni = 0; ni < 4; ++ni)
              if (kt * 64 + ni * 16 + ll > qg) s[mi][ni][j] = NEGBIG;
          }
          lm[mi][j] = fmaxf(fmaxf(s[mi][0][j], s[mi][1][j]),
                            fmaxf(s[mi][2][j], s[mi][3][j]));
        }
      float excess = lm[0][0] - m_[0][0];
#pragma unroll
      for (int mi = 0; mi < 2; ++mi)
#pragma unroll
        for (int j = 0; j < 4; ++j) excess = fmaxf(excess, lm[mi][j] - m_[mi][j]);
      const bool slow = __any(excess > 11.5f);

#pragma unroll
      for (int mi = 0; mi < 2; ++mi)
#pragma unroll
        for (int j = 0; j < 4; ++j) {
          float ps_[4];
          if (slow) {
            float mt = lm[mi][j];
            mt = fmaxf(mt, __shfl_xor(mt, 1));
            mt = fmaxf(mt, __shfl_xor(mt, 2));
            mt = fmaxf(mt, __shfl_xor(mt, 4));
            mt = fmaxf(mt, __shfl_xor(mt, 8));
            const float mnew = fmaxf(m_[mi][j], mt);
            const float al = exp2f(m_[mi][j] - mnew);
            m_[mi][j] = mnew;
            float sum = 0.f;
#pragma unroll
            for (int ni = 0; ni < 4; ++ni) { ps_[ni] = exp2f(s[mi][ni][j] - mnew); sum += ps_[ni]; }
            l_[mi][j] = l_[mi][j] * al + sum;
#pragma unroll
            for (int nd = 0; nd < 8; ++nd) o[mi][nd][j] *= al;
          } else {
            float sum = 0.f;
#pragma unroll
            for (int ni = 0; ni < 4; ++ni) { ps_[ni] = exp2f(s[mi][ni][j] - m_[mi][j]); sum += ps_[ni]; }
            l_[mi][j] += sum;
          }
          const int prow = mi * 16 + lg * 4 + j;
#pragma unroll
          for (int nq = 0; nq < 2; ++nq) {
            unsigned int u;
            asm("v_cvt_pk_bf16_f32 %0, %1, %2" : "=v"(u) : "v"(ps_[nq * 2]), "v"(ps_[nq * 2 + 1]));
            const int c0 = nq * 32 + ll, c1 = nq * 32 + 16 + ll;
            Ps[w][prow * 64 + (((c0 >> 3) ^ (prow & 7)) * 8) + (ll & 7)] = (unsigned short)u;
            Ps[w][prow * 64 + (((c1 >> 3) ^ (prow & 7)) * 8) + (ll & 7)] = (unsigned short)(u >> 16);
          }
        }

      s16x8 pa[2][2];
#pragma unroll
      for (int mi = 0; mi < 2; ++mi)
#pragma unroll
        for (int ks2 = 0; ks2 < 2; ++ks2) {
          const int prow = mi * 16 + ll;
          pa[mi][ks2] = *(const s16x8*)&Ps[w][prow * 64 + (((ks2 * 4 + lg) ^ (prow & 7)) * 8)];
        }
#pragma unroll
      for (int nd = 0; nd < 8; ++nd) {
#pragma unroll
        for (int ks2 = 0; ks2 < 2; ++ks2) {
          const int vr = nd * 16 + ll;
          const s16x8 vbf = *(const s16x8*)&Vt[p][vr * 64 + (((ks2 * 4 + lg) ^ (vr & 7)) * 8)];
          o[0][nd] = __builtin_amdgcn_mfma_f32_16x16x32_bf16(pa[0][ks2], vbf, o[0][nd], 0, 0, 0);
          o[1][nd] = __builtin_amdgcn_mfma_f32_16x16x32_bf16(pa[1][ks2], vbf, o[1][nd], 0, 0, 0);
        }
      }
    }

    if (kt < ktend) {
#pragma unroll
      for (int j = 0; j < 8; ++j) {
        const int d1 = d0v + j, d2 = d0v + 8 + j;
        *(unsigned int*)&Vt[p ^ 1][d1 * 64 + (((vk >> 3) ^ (d1 & 7)) * 8) + (vk & 7)] =
            (unsigned int)va0[j] | ((unsigned int)vb0[j] << 16);
        *(unsigned int*)&Vt[p ^ 1][d2 * 64 + (((vk >> 3) ^ (d2 & 7)) * 8) + (vk & 7)] =
            (unsigned int)va1[j] | ((unsigned int)vb1[j] << 16);
      }
    }
    __syncthreads();
  }

#pragma unroll
  for (int mi = 0; mi < 2; ++mi)
#pragma unroll
    for (int j = 0; j < 4; ++j) {
      float ls = l_[mi][j];
      ls += __shfl_xor(ls, 1);
      ls += __shfl_xor(ls, 2);
      ls += __shfl_xor(ls, 4);
      ls += __shfl_xor(ls, 8);
      if constexpr (SPLIT) {
        unsigned short* Ph = half ? P1 : P0;
        float2* mlh = half ? ml1 : ml0;
        const size_t ridx = ((size_t)b * NH_ + h) * S_ + qr0 + mi * 16 + lg * 4 + j;
        unsigned short* op = &Ph[ridx * D_ + ll];
#pragma unroll
        for (int nd = 0; nd < 8; ++nd) op[nd * 16] = f2bf(o[mi][nd][j]);
        if (ll == 0) mlh[ridx] = make_float2(m_[mi][j], ls);
      } else {
        const float inv = 1.f / ls;
        const size_t rowg = (size_t)b * S_ + qr0 + mi * 16 + lg * 4 + j;
        unsigned short* op = &outp[rowg * (NH_ * D_) + h * D_ + ll];
#pragma unroll
        for (int nd = 0; nd < 8; ++nd) op[nd * 16] = f2bf(o[mi][nd][j] * inv);
      }
    }
}

// ---------------------------------------------------------------------------
// Combine split-KV partials.
// ---------------------------------------------------------------------------
__global__ __launch_bounds__(256) void attn_combine(const unsigned short* __restrict__ P0,
                                                    const unsigned short* __restrict__ P1,
                                                    const float2* __restrict__ ml0,
                                                    const float2* __restrict__ ml1,
                                                    unsigned short* __restrict__ outp) {
  const int s = blockIdx.x, b = blockIdx.y;
  const int tid = threadIdx.x;
  const int h = tid >> 4, d0 = (tid & 15) * 8;
  const size_t ridx = ((size_t)b * NH_ + h) * S_ + s;
  const float2 a = ml0[ridx], c = ml1[ridx];
  const float m = fmaxf(a.x, c.x);
  const float a0 = exp2f(a.x - m), a1 = exp2f(c.x - m);
  const float inv = 1.f / (a0 * a.y + a1 * c.y);
  const ushort8 u0 = *(const ushort8*)&P0[ridx * D_ + d0];
  const ushort8 u1 = *(const ushort8*)&P1[ridx * D_ + d0];
  ushort8 r;
#pragma unroll
  for (int j = 0; j < 8; ++j)
    r[j] = f2bf((a0 * bf2f(u0[j]) + a1 * bf2f(u1[j])) * inv);
  *(ushort8*)&outp[((size_t)b * S_ + s) * (NH_ * D_) + h * D_ + d0] = r;
}

// ---------------------------------------------------------------------------
// Host launch
// ---------------------------------------------------------------------------
extern "C" void kernel_launch(void* const* d_in, const int* in_sizes, int n_in,
                              void* d_out, int out_size, void* d_ws, size_t ws_size,
                              hipStream_t stream) {
  const float* hidden = (const float*)d_in[0];
  const float* cosT   = (const float*)d_in[1];
  const float* sinT   = (const float*)d_in[2];
  const float* W_q    = (const float*)d_in[5];
  const float* W_k    = (const float*)d_in[6];
  const float* W_v    = (const float*)d_in[7];
  const float* W_o    = (const float*)d_in[8];
  const float* Vr     = (const float*)d_in[9];
  const float* Zv     = (const float*)d_in[10];
  float* out = (float*)d_out;

  char* ws = (char*)d_ws;
  unsigned short* hb     = (unsigned short*)(ws + 0);
  unsigned short* attn_b = (unsigned short*)(ws + 0);
  unsigned short* P0     = (unsigned short*)(ws + 0);
  unsigned short* q_b    = (unsigned short*)(ws + 33554432);
  unsigned short* kr_b   = (unsigned short*)(ws + 67108864);
  unsigned short* Wf     = (unsigned short*)(ws + 100663296);
  unsigned short* vh_b   = (unsigned short*)(ws + 100663296);
  unsigned short* WR1    = (unsigned short*)(ws + 117440512);
  float*          pkpv   = (float*)(ws + 117440512);
  unsigned short* P1     = (unsigned short*)(ws + 130023424);
  float2*         ml0    = (float2*)(ws + 163577856);
  float2*         ml1    = (float2*)(ws + 164626432);
  const size_t NEED_SPLIT = 165675008ull;
  const bool split = (ws_size >= NEED_SPLIT);

  const int M = B_ * S_;

  // 1) conversions + Q projection (8-phase 256^2)
  cvt_bf16<<<2048, 256, 0, stream>>>(hidden, hb, (B_ * S_ * HID_) / 8);
  cvt_bf16<<<2048, 256, 0, stream>>>(W_q, WR1, (HID_ * HID_) / 8);
  gemm256_8ph<true><<<dim3(8, 32), 512, 0, stream>>>(hb, WR1, q_b, M, 2048, HID_);

  // 2) fused low-rank weights + direct pk|pv GEMM (m97 path, N=384)
  wfuse<<<dim3(24, 8), 256, 0, stream>>>(W_k, W_v, Vr, Zv, Wf);
  gemm_mfma<false><<<dim3(3, 64), 256, 0, stream>>>(hb, Wf, pkpv, M, 384, HID_);

  // 3) rope(q) in place
  rope_q<<<(B_ * S_ * NH_ * 64) / 256, 256, 0, stream>>>(q_b, cosT, sinT);

  // 4) expand K (+rope) and V
  expand_k<<<dim3(S_ / 32, NH_, B_), 256, 0, stream>>>(pkpv, Vr, cosT, sinT, kr_b);
  expand_v<<<dim3(S_ / 32, NKV_, B_), 256, 0, stream>>>(pkpv, Zv, vh_b);

  // 5) Wo conversion (pkpv dead after expanders)
  cvt_bf16<<<2048, 256, 0, stream>>>(W_o, WR1, (HID_ * HID_) / 8);

  // 6) attention
  if (split) {
    attn_mfma<true><<<dim3(32, 16, 4), 256, 0, stream>>>(q_b, kr_b, vh_b, nullptr,
                                                         P0, P1, ml0, ml1);
    attn_combine<<<dim3(S_, B_), 256, 0, stream>>>(P0, P1, ml0, ml1, q_b);
    gemm256_8ph<false><<<dim3(8, 32), 512, 0, stream>>>(q_b, WR1, out, M, HID_, HID_);
  } else {
    attn_mfma<false><<<dim3(16, 16, 4), 256, 0, stream>>>(q_b, kr_b, vh_b, attn_b,
                                                          nullptr, nullptr, nullptr, nullptr);
    gemm256_8ph<false><<<dim3(8, 32), 512, 0, stream>>>(attn_b, WR1, out, M, HID_, HID_);
  }
}